// Round 2
// baseline (422.509 us; speedup 1.0000x reference)
//
#include <hip/hip_runtime.h>
#include <hip/hip_bf16.h>
#include <math.h>

#define BB 1024
#define TT 64
#define DD 256
#define PP 2048
#define HH 512

typedef __attribute__((ext_vector_type(8))) short short8;
typedef __attribute__((ext_vector_type(4))) short short4v;
typedef __attribute__((ext_vector_type(4))) float f32x4;

__device__ __forceinline__ float4 f4add(float4 a, float4 b) {
    return make_float4(a.x + b.x, a.y + b.y, a.z + b.z, a.w + b.w);
}

__device__ __forceinline__ void nt_store4(float* p, float4 v) {
    f32x4 t = {v.x, v.y, v.z, v.w};
    __builtin_nontemporal_store(t, (f32x4*)p);
}

__device__ __forceinline__ void nt_store1(float* p, float v) {
    __builtin_nontemporal_store(v, p);
}

__device__ __forceinline__ void store_bf16x4(__hip_bfloat16* dst, float4 m) {
    union { __hip_bfloat16 h[4]; short4v s; } u;
    u.h[0] = __float2bfloat16(m.x); u.h[1] = __float2bfloat16(m.y);
    u.h[2] = __float2bfloat16(m.z); u.h[3] = __float2bfloat16(m.w);
    *(short4v*)dst = u.s;
}

// ================ K1: prep — wave-per-row reductions, NO LDS, NO barriers ======
// blocks 0..767:    row reduce (4 rows/block, 1 wave per [64,256] row)
// blocks 768..1535: weight convert+transpose (4 elems/thread) + colsum zero
__global__ void prep_k(const float* __restrict__ cf, const float* __restrict__ proto,
                       const float* __restrict__ dd_w1, const float* __restrict__ dd_w2,
                       const float* __restrict__ cal_w1, const float* __restrict__ cal_w2,
                       const float* __restrict__ cal_w3,
                       float* __restrict__ ffm, float* __restrict__ fn,
                       float* __restrict__ pn, float* __restrict__ pc,
                       float* __restrict__ colsum,
                       __hip_bfloat16* __restrict__ ffb, __hip_bfloat16* __restrict__ pcb,
                       __hip_bfloat16* __restrict__ w1cat, __hip_bfloat16* __restrict__ w2dd,
                       __hip_bfloat16* __restrict__ w2cal, __hip_bfloat16* __restrict__ w3cal) {
    int b = blockIdx.x, tid = threadIdx.x;
    if (b < 768) {                          // 4 rows per block, wave w owns row 4b+w
        int wv = tid >> 6, lane = tid & 63;
        int row = (b << 2) + wv;            // 0..3071 (0..1023 cf, 1024..3071 proto)
        const float* base = (row < 1024) ? cf + (size_t)row * TT * DD
                                         : proto + (size_t)(row - 1024) * TT * DD;
        const float* p = base + (lane << 2);
        float4 acc = make_float4(0.f, 0.f, 0.f, 0.f);
        float4 v[16];
        #pragma unroll
        for (int tb = 0; tb < TT; tb += 16) {
            #pragma unroll
            for (int i = 0; i < 16; ++i)
                v[i] = *(const float4*)(p + (size_t)(tb + i) * DD);
            #pragma unroll
            for (int i = 0; i < 8; ++i) v[i] = f4add(v[i], v[i + 8]);
            #pragma unroll
            for (int i = 0; i < 4; ++i) v[i] = f4add(v[i], v[i + 4]);
            acc = f4add(acc, f4add(f4add(v[0], v[1]), f4add(v[2], v[3])));
        }
        float4 m = make_float4(acc.x * (1.f / TT), acc.y * (1.f / TT),
                               acc.z * (1.f / TT), acc.w * (1.f / TT));
        if (row < 1024) {
            *(float4*)(ffm + (size_t)row * DD + (lane << 2)) = m;
            store_bf16x4(ffb + (size_t)row * DD + (lane << 2), m);
        } else {
            int r = row - 1024;
            *(float4*)(pc + (size_t)r * DD + (lane << 2)) = m;
            store_bf16x4(pcb + (size_t)r * DD + (lane << 2), m);
        }
        float q = m.x * m.x + m.y * m.y + m.z * m.z + m.w * m.w;
        #pragma unroll
        for (int o = 32; o > 0; o >>= 1) q += __shfl_xor(q, o, 64);
        if (lane == 0) {
            float nv = fmaxf(sqrtf(q), 1e-8f);
            if (row < 1024) fn[row] = nv; else pn[row - 1024] = nv;
        }
    } else {                                // weight convert+transpose, 4 elems/thread
        int bb = b - 768;
        if (bb < 8) colsum[bb * 256 + tid] = 0.f;
        #pragma unroll
        for (int i2 = 0; i2 < 4; ++i2) {
            int idx = bb * 1024 + i2 * 256 + tid;
            if (idx < 262144) {               // w1cat: dd_w1 | cal_w1, K=256 N=512 each
                int half = idx >> 17;
                int i = idx & 131071;
                int n = i & 511, k = i >> 9;
                const float* src = half ? cal_w1 : dd_w1;
                w1cat[(size_t)(half * 512 + n) * 256 + k] = __float2bfloat16(src[(size_t)k * 512 + n]);
            } else if (idx < 393216) {        // w2dd: K=512 N=256
                int i = idx - 262144;
                int n = i & 255, k = i >> 8;
                w2dd[(size_t)n * 512 + k] = __float2bfloat16(dd_w2[(size_t)k * 256 + n]);
            } else if (idx < 655360) {        // w2cal: K=512 N=512
                int i = idx - 393216;
                int n = i & 511, k = i >> 9;
                w2cal[(size_t)n * 512 + k] = __float2bfloat16(cal_w2[(size_t)k * 512 + n]);
            } else {                          // w3cal: K=512 N=256
                int i = idx - 655360;
                int n = i & 255, k = i >> 8;
                w3cal[(size_t)n * 512 + k] = __float2bfloat16(cal_w3[(size_t)k * 256 + n]);
            }
        }
    }
}

// ================ K2: sim MFMA + addvec, role by blockIdx =====================
__global__ void sim_addvec_k(const __hip_bfloat16* __restrict__ A,
                             const __hip_bfloat16* __restrict__ Bt,
                             const float* __restrict__ fn, const float* __restrict__ pn,
                             const float* __restrict__ ffm,
                             const float* __restrict__ dd_w1, const float* __restrict__ dd_b1,
                             float* __restrict__ drift, float* __restrict__ colsum,
                             float* __restrict__ addvec) {
    if (blockIdx.x >= 512) {              // addvec role: 2 blocks x 256 j's
        __shared__ float gmk[256];
        int tid = threadIdx.x;
        const float* f = ffm + tid;
        float a0 = 0.f, a1 = 0.f, a2 = 0.f, a3 = 0.f, a4 = 0.f, a5 = 0.f, a6 = 0.f, a7 = 0.f;
        #pragma unroll 4
        for (int b = 0; b < 1024; b += 8) {
            a0 += f[(b + 0) << 8]; a1 += f[(b + 1) << 8];
            a2 += f[(b + 2) << 8]; a3 += f[(b + 3) << 8];
            a4 += f[(b + 4) << 8]; a5 += f[(b + 5) << 8];
            a6 += f[(b + 6) << 8]; a7 += f[(b + 7) << 8];
        }
        gmk[tid] = (((a0 + a1) + (a2 + a3)) + ((a4 + a5) + (a6 + a7))) * (1.f / BB);
        __syncthreads();
        int j = (blockIdx.x - 512) * 256 + tid;
        float s = dd_b1[j];
        #pragma unroll 8
        for (int k = 0; k < 256; ++k) s = fmaf(gmk[k], dd_w1[(size_t)(256 + k) * 512 + j], s);
        addvec[j] = s;
        return;
    }
    int wid = (blockIdx.x << 2) + (threadIdx.x >> 6);   // 0..2047
    int lane = threadIdx.x & 63;
    int mw = wid >> 6, nw = wid & 63;
    int m0 = mw << 5, n0 = nw << 5;
    int lr = lane & 15, quad = lane >> 4;
    const __hip_bfloat16* pa0 = A + (size_t)(m0 + lr) * DD + quad * 8;
    const __hip_bfloat16* pa1 = pa0 + 16 * DD;
    const __hip_bfloat16* pb0 = Bt + (size_t)(n0 + lr) * DD + quad * 8;
    const __hip_bfloat16* pb1 = pb0 + 16 * DD;
    f32x4 acc00 = {0,0,0,0}, acc01 = {0,0,0,0}, acc10 = {0,0,0,0}, acc11 = {0,0,0,0};
    #pragma unroll
    for (int k = 0; k < DD; k += 32) {
        short8 a0 = *(const short8*)(pa0 + k);
        short8 a1 = *(const short8*)(pa1 + k);
        short8 b0 = *(const short8*)(pb0 + k);
        short8 b1 = *(const short8*)(pb1 + k);
        acc00 = __builtin_amdgcn_mfma_f32_16x16x32_bf16(a0, b0, acc00, 0, 0, 0);
        acc01 = __builtin_amdgcn_mfma_f32_16x16x32_bf16(a0, b1, acc01, 0, 0, 0);
        acc10 = __builtin_amdgcn_mfma_f32_16x16x32_bf16(a1, b0, acc10, 0, 0, 0);
        acc11 = __builtin_amdgcn_mfma_f32_16x16x32_bf16(a1, b1, acc11, 0, 0, 0);
    }
    int col0 = n0 + lr, col1 = col0 + 16;
    float ip0 = 1.f / pn[col0], ip1 = 1.f / pn[col1];
    float cs0 = 0.f, cs1 = 0.f;
    #pragma unroll
    for (int r = 0; r < 4; ++r) {
        int row0 = m0 + quad * 4 + r;
        int row1 = row0 + 16;
        float if0 = 1.f / fn[row0];
        float if1 = 1.f / fn[row1];
        float d00 = 1.f - acc00[r] * if0 * ip0;
        float d01 = 1.f - acc01[r] * if0 * ip1;
        float d10 = 1.f - acc10[r] * if1 * ip0;
        float d11 = 1.f - acc11[r] * if1 * ip1;
        nt_store1(&drift[(size_t)row0 * PP + col0], d00);
        nt_store1(&drift[(size_t)row0 * PP + col1], d01);
        nt_store1(&drift[(size_t)row1 * PP + col0], d10);
        nt_store1(&drift[(size_t)row1 * PP + col1], d11);
        cs0 += d00 + d10;
        cs1 += d01 + d11;
    }
    cs0 += __shfl_xor(cs0, 16, 64); cs0 += __shfl_xor(cs0, 32, 64);
    cs1 += __shfl_xor(cs1, 16, 64); cs1 += __shfl_xor(cs1, 32, 64);
    if (quad == 0) {
        atomicAdd(&colsum[col0], cs0);
        atomicAdd(&colsum[col1], cs1);
    }
}

// ================ K3: fused layer-1 GEMM + LayerNorm + ReLU -> bf16 ===========
// 128 blocks x 256 threads. Block: h = bid>>6 (0 dd, 1 cal), 32 rows x 512 cols.
// Wave wv owns cols [wv*128, wv*128+128) as 4 32x32 tiles; LN stats combined
// in-wave (shfl butterflies) + 1KB LDS across the 4 waves.
__global__ void gemm1ln_k(const __hip_bfloat16* __restrict__ pcb,
                          const __hip_bfloat16* __restrict__ w1cat,
                          const float* __restrict__ addvec, const float* __restrict__ cal_b1,
                          const float* __restrict__ gdd, const float* __restrict__ bedd,
                          const float* __restrict__ gcal, const float* __restrict__ becal,
                          __hip_bfloat16* __restrict__ Ydd, __hip_bfloat16* __restrict__ Ycal) {
    __shared__ float lds_s[4][32];
    __shared__ float lds_q[4][32];
    int h = blockIdx.x >> 6;                 // 0: dd, 1: cal
    int r0 = (blockIdx.x & 63) << 5;         // row base
    int wv = threadIdx.x >> 6;               // wave 0..3
    int lane = threadIdx.x & 63;
    int lr = lane & 15, quad = lane >> 4;
    const float* bias = h ? cal_b1 : addvec;
    const float* g    = h ? gcal : gdd;
    const float* be   = h ? becal : bedd;
    __hip_bfloat16* Y = h ? Ycal : Ydd;

    const __hip_bfloat16* pa0 = pcb + (size_t)(r0 + lr) * DD + quad * 8;
    const __hip_bfloat16* pa1 = pa0 + 16 * DD;

    f32x4 a00[4], a01[4], a10[4], a11[4];
    float bi0[4], bi1[4];
    #pragma unroll
    for (int t = 0; t < 4; ++t) {
        int n0g = h * 512 + wv * 128 + t * 32;      // col in w1cat [1024][256]
        const __hip_bfloat16* pb0 = w1cat + (size_t)(n0g + lr) * DD + quad * 8;
        const __hip_bfloat16* pb1 = pb0 + 16 * DD;
        f32x4 c00 = {0,0,0,0}, c01 = {0,0,0,0}, c10 = {0,0,0,0}, c11 = {0,0,0,0};
        #pragma unroll
        for (int k = 0; k < DD; k += 32) {
            short8 av0 = *(const short8*)(pa0 + k);
            short8 av1 = *(const short8*)(pa1 + k);
            short8 bv0 = *(const short8*)(pb0 + k);
            short8 bv1 = *(const short8*)(pb1 + k);
            c00 = __builtin_amdgcn_mfma_f32_16x16x32_bf16(av0, bv0, c00, 0, 0, 0);
            c01 = __builtin_amdgcn_mfma_f32_16x16x32_bf16(av0, bv1, c01, 0, 0, 0);
            c10 = __builtin_amdgcn_mfma_f32_16x16x32_bf16(av1, bv0, c10, 0, 0, 0);
            c11 = __builtin_amdgcn_mfma_f32_16x16x32_bf16(av1, bv1, c11, 0, 0, 0);
        }
        a00[t] = c00; a01[t] = c01; a10[t] = c10; a11[t] = c11;
        int cl0 = wv * 128 + t * 32 + lr;           // col within half (0..511)
        bi0[t] = bias[cl0];
        bi1[t] = bias[cl0 + 16];
    }

    // add bias, accumulate per-row partial sum / sumsq over this wave's 128 cols
    float ps_lo[4] = {0,0,0,0}, pq_lo[4] = {0,0,0,0};
    float ps_hi[4] = {0,0,0,0}, pq_hi[4] = {0,0,0,0};
    #pragma unroll
    for (int t = 0; t < 4; ++t) {
        #pragma unroll
        for (int r = 0; r < 4; ++r) {
            float v00 = a00[t][r] + bi0[t];
            float v01 = a01[t][r] + bi1[t];
            float v10 = a10[t][r] + bi0[t];
            float v11 = a11[t][r] + bi1[t];
            a00[t][r] = v00; a01[t][r] = v01; a10[t][r] = v10; a11[t][r] = v11;
            ps_lo[r] += v00 + v01;  pq_lo[r] += v00 * v00 + v01 * v01;
            ps_hi[r] += v10 + v11;  pq_hi[r] += v10 * v10 + v11 * v11;
        }
    }
    // butterfly across the 16 lanes of this quad (masks 1,2,4,8 keep quad bits)
    #pragma unroll
    for (int mset = 1; mset < 16; mset <<= 1) {
        #pragma unroll
        for (int r = 0; r < 4; ++r) {
            ps_lo[r] += __shfl_xor(ps_lo[r], mset, 64);
            pq_lo[r] += __shfl_xor(pq_lo[r], mset, 64);
            ps_hi[r] += __shfl_xor(ps_hi[r], mset, 64);
            pq_hi[r] += __shfl_xor(pq_hi[r], mset, 64);
        }
    }
    // lanes lr<8 publish: rows quad*4+(lr&3) (+16 for lr>=4)
    if (lr < 8) {
        int rr = quad * 4 + (lr & 3) + ((lr >> 2) << 4);
        lds_s[wv][rr] = (lr >= 4) ? ps_hi[lr & 3] : ps_lo[lr & 3];
        lds_q[wv][rr] = (lr >= 4) ? pq_hi[lr & 3] : pq_lo[lr & 3];
    }
    __syncthreads();

    float mu_lo[4], rs_lo[4], mu_hi[4], rs_hi[4];
    #pragma unroll
    for (int r = 0; r < 4; ++r) {
        int rl = quad * 4 + r;
        float s = lds_s[0][rl] + lds_s[1][rl] + lds_s[2][rl] + lds_s[3][rl];
        float q = lds_q[0][rl] + lds_q[1][rl] + lds_q[2][rl] + lds_q[3][rl];
        float mu = s * (1.f / HH);
        float var = fmaxf(q * (1.f / HH) - mu * mu, 0.f);
        mu_lo[r] = mu; rs_lo[r] = rsqrtf(var + 1e-5f);
        int rh = rl + 16;
        s = lds_s[0][rh] + lds_s[1][rh] + lds_s[2][rh] + lds_s[3][rh];
        q = lds_q[0][rh] + lds_q[1][rh] + lds_q[2][rh] + lds_q[3][rh];
        mu = s * (1.f / HH);
        var = fmaxf(q * (1.f / HH) - mu * mu, 0.f);
        mu_hi[r] = mu; rs_hi[r] = rsqrtf(var + 1e-5f);
    }

    #pragma unroll
    for (int t = 0; t < 4; ++t) {
        int c0 = wv * 128 + t * 32 + lr, c1 = c0 + 16;
        float g0 = g[c0], g1 = g[c1], b0 = be[c0], b1 = be[c1];
        #pragma unroll
        for (int r = 0; r < 4; ++r) {
            int row = r0 + quad * 4 + r;
            float y00 = fmaxf((a00[t][r] - mu_lo[r]) * rs_lo[r] * g0 + b0, 0.f);
            float y01 = fmaxf((a01[t][r] - mu_lo[r]) * rs_lo[r] * g1 + b1, 0.f);
            float y10 = fmaxf((a10[t][r] - mu_hi[r]) * rs_hi[r] * g0 + b0, 0.f);
            float y11 = fmaxf((a11[t][r] - mu_hi[r]) * rs_hi[r] * g1 + b1, 0.f);
            Y[(size_t)row * HH + c0]        = __float2bfloat16(y00);
            Y[(size_t)row * HH + c1]        = __float2bfloat16(y01);
            Y[(size_t)(row + 16) * HH + c0] = __float2bfloat16(y10);
            Y[(size_t)(row + 16) * HH + c1] = __float2bfloat16(y11);
        }
    }
}

// ================ 32x32 MFMA tile device function ============================
template <int K, int OUT_BF16, int RELU>
__device__ __forceinline__ void gemm_tile(const __hip_bfloat16* __restrict__ A,
                                          const __hip_bfloat16* __restrict__ Bt,
                                          const float* __restrict__ bias0,
                                          const float* __restrict__ bias1, int split,
                                          void* __restrict__ Cout, int N, int lognt,
                                          int wid, int lane) {
    int mw = wid >> lognt, nw = wid & ((1 << lognt) - 1);
    int m0 = mw << 5, n0 = nw << 5;
    int lr = lane & 15, quad = lane >> 4;
    const __hip_bfloat16* pa0 = A + (size_t)(m0 + lr) * K + quad * 8;
    const __hip_bfloat16* pa1 = pa0 + 16 * K;
    const __hip_bfloat16* pb0 = Bt + (size_t)(n0 + lr) * K + quad * 8;
    const __hip_bfloat16* pb1 = pb0 + 16 * K;
    f32x4 acc00 = {0,0,0,0}, acc01 = {0,0,0,0}, acc10 = {0,0,0,0}, acc11 = {0,0,0,0};
    #pragma unroll
    for (int k = 0; k < K; k += 32) {
        short8 a0 = *(const short8*)(pa0 + k);
        short8 a1 = *(const short8*)(pa1 + k);
        short8 b0 = *(const short8*)(pb0 + k);
        short8 b1 = *(const short8*)(pb1 + k);
        acc00 = __builtin_amdgcn_mfma_f32_16x16x32_bf16(a0, b0, acc00, 0, 0, 0);
        acc01 = __builtin_amdgcn_mfma_f32_16x16x32_bf16(a0, b1, acc01, 0, 0, 0);
        acc10 = __builtin_amdgcn_mfma_f32_16x16x32_bf16(a1, b0, acc10, 0, 0, 0);
        acc11 = __builtin_amdgcn_mfma_f32_16x16x32_bf16(a1, b1, acc11, 0, 0, 0);
    }
    int col0 = n0 + lr, col1 = col0 + 16;
    float bi0 = (col0 < split) ? bias0[col0] : bias1[col0 - split];
    float bi1 = (col1 < split) ? bias0[col1] : bias1[col1 - split];
    #pragma unroll
    for (int r = 0; r < 4; ++r) {
        int row0 = m0 + quad * 4 + r;
        int row1 = row0 + 16;
        float v00 = acc00[r] + bi0, v01 = acc01[r] + bi1;
        float v10 = acc10[r] + bi0, v11 = acc11[r] + bi1;
        if (RELU) {
            v00 = fmaxf(v00, 0.f); v01 = fmaxf(v01, 0.f);
            v10 = fmaxf(v10, 0.f); v11 = fmaxf(v11, 0.f);
        }
        if (OUT_BF16) {
            __hip_bfloat16* C = (__hip_bfloat16*)Cout;
            C[(size_t)row0 * N + col0] = __float2bfloat16(v00);
            C[(size_t)row0 * N + col1] = __float2bfloat16(v01);
            C[(size_t)row1 * N + col0] = __float2bfloat16(v10);
            C[(size_t)row1 * N + col1] = __float2bfloat16(v11);
        } else {
            float* C = (float*)Cout;
            C[(size_t)row0 * N + col0] = v00;
            C[(size_t)row0 * N + col1] = v01;
            C[(size_t)row1 * N + col0] = v10;
            C[(size_t)row1 * N + col1] = v11;
        }
    }
}

// ================ K4: dd2 + cal2 GEMMs, role by blockIdx ======================
__global__ void gemm2_k(const __hip_bfloat16* __restrict__ act_dd,
                        const __hip_bfloat16* __restrict__ act_cal,
                        const __hip_bfloat16* __restrict__ w2dd,
                        const __hip_bfloat16* __restrict__ w2cal,
                        const float* __restrict__ dd_b2, const float* __restrict__ cal_b2,
                        __hip_bfloat16* __restrict__ act2b, __hip_bfloat16* __restrict__ act3b) {
    int lane = threadIdx.x & 63;
    if (blockIdx.x < 128) {   // dd2: [2048,512]@[512,256] -> act2b
        int wid = (blockIdx.x << 2) + (threadIdx.x >> 6);
        gemm_tile<512, 1, 1>(act_dd, w2dd, dd_b2, dd_b2, 1 << 30, act2b, 256, 3, wid, lane);
    } else {                  // cal2: [2048,512]@[512,512] -> act3b
        int wid = ((blockIdx.x - 128) << 2) + (threadIdx.x >> 6);
        gemm_tile<512, 1, 1>(act_cal, w2cal, cal_b2, cal_b2, 1 << 30, act3b, 512, 4, wid, lane);
    }
}

// ================ K5: cal3 GEMM + conf/sigmoid/is_drifted =====================
__global__ void gemm3_conf_k(const __hip_bfloat16* __restrict__ act3b,
                             const __hip_bfloat16* __restrict__ w3cal,
                             const float* __restrict__ cal_b3,
                             const __hip_bfloat16* __restrict__ act2b,
                             const float* __restrict__ dd_w3, const float* __restrict__ dd_b3,
                             const float* __restrict__ colsum,
                             float* __restrict__ delta, float* __restrict__ strength,
                             float* __restrict__ out_is) {
    if (blockIdx.x < 128) {   // cal3: [2048,512]@[512,256] -> delta fp32
        int wid = (blockIdx.x << 2) + (threadIdx.x >> 6);
        gemm_tile<512, 0, 0>(act3b, w3cal, cal_b3, cal_b3, 1 << 30, delta, 256, 3,
                             wid, threadIdx.x & 63);
        return;
    }
    // conf role: one wave per p, blocks 128..639
    int p = ((blockIdx.x - 128) << 2) + (threadIdx.x >> 6);   // 0..2047
    int lane = threadIdx.x & 63;
    const __hip_bfloat16* row = act2b + (size_t)p * 256 + lane * 4;
    float s = 0.f;
    #pragma unroll
    for (int j = 0; j < 4; ++j)
        s += __bfloat162float(row[j]) * dd_w3[lane * 4 + j];
    #pragma unroll
    for (int o = 32; o > 0; o >>= 1) s += __shfl_down(s, o, 64);
    if (lane == 0) {
        float conf = 1.f / (1.f + expf(-(s + dd_b3[0])));
        strength[p] = fminf(fmaxf(0.1f * conf, 0.f), 0.5f);
        out_is[p] = (colsum[p] * (1.f / BB) > 0.3f) ? 1.f : 0.f;
    }
}

// ================ K6: write calibrated [P,T,D], nontemporal float4 ============
__global__ void finalize_k(const float* __restrict__ pc, const float* __restrict__ delta,
                           const float* __restrict__ strength, const float* __restrict__ colsum,
                           const float* __restrict__ proto, float* __restrict__ out) {
    int p = blockIdx.x;
    int d4 = (threadIdx.x & 63) << 2;
    int t0 = threadIdx.x >> 6;
    bool dr = colsum[p] * (1.f / BB) > 0.3f;
    float* o = out + (size_t)p * TT * DD;
    if (dr) {
        float s = strength[p];
        float4 pcv = *(const float4*)(pc + (size_t)p * DD + d4);
        float4 dv  = *(const float4*)(delta + (size_t)p * DD + d4);
        float4 nc = make_float4(fmaf(s, dv.x, pcv.x), fmaf(s, dv.y, pcv.y),
                                fmaf(s, dv.z, pcv.z), fmaf(s, dv.w, pcv.w));
        #pragma unroll
        for (int t = t0; t < TT; t += 4)
            nt_store4(o + t * DD + d4, nc);
    } else {
        const float* pr = proto + (size_t)p * TT * DD;
        #pragma unroll
        for (int t = t0; t < TT; t += 4)
            nt_store4(o + t * DD + d4, *(const float4*)(pr + t * DD + d4));
    }
}

extern "C" void kernel_launch(void* const* d_in, const int* in_sizes, int n_in,
                              void* d_out, int out_size, void* d_ws, size_t ws_size,
                              hipStream_t stream) {
    const float* cf     = (const float*)d_in[0];
    const float* proto  = (const float*)d_in[1];
    const float* dd_w1  = (const float*)d_in[2];
    const float* dd_b1  = (const float*)d_in[3];
    const float* dd_g1  = (const float*)d_in[4];
    const float* dd_be1 = (const float*)d_in[5];
    const float* dd_w2  = (const float*)d_in[6];
    const float* dd_b2  = (const float*)d_in[7];
    const float* dd_w3  = (const float*)d_in[8];
    const float* dd_b3  = (const float*)d_in[9];
    const float* cal_w1 = (const float*)d_in[10];
    const float* cal_b1 = (const float*)d_in[11];
    const float* cal_g1 = (const float*)d_in[12];
    const float* cal_be1= (const float*)d_in[13];
    const float* cal_w2 = (const float*)d_in[14];
    const float* cal_b2 = (const float*)d_in[15];
    const float* cal_w3 = (const float*)d_in[16];
    const float* cal_b3 = (const float*)d_in[17];

    float* out_cal   = (float*)d_out;
    float* out_drift = out_cal + (size_t)PP * TT * DD;
    float* out_is    = out_drift + (size_t)BB * PP;

    float* w = (float*)d_ws;
    float* colsum   = w;               // 2048 (zeroed inside prep_k)
    float* addvec   = w + 4096;        // 512
    float* fn       = w + 4608;        // 1024
    float* pn       = w + 5632;        // 2048
    float* strength = w + 7680;        // 2048
    float* pc       = w + 9728;        // 2048*256
    float* ffm      = w + 534016;      // 1024*256 fp32 (gmean source)
    float* delta    = w + 2631168;     // 2048*256
    __hip_bfloat16* bb = (__hip_bfloat16*)(w + 3155456);
    __hip_bfloat16* ffb     = bb;                 // 1024*256
    __hip_bfloat16* pcb     = bb + 262144;        // 2048*256
    __hip_bfloat16* w1cat   = bb + 786432;        // 1024*256
    __hip_bfloat16* w2dd    = bb + 1048576;       // 256*512
    __hip_bfloat16* w2cal   = bb + 1179648;       // 512*512
    __hip_bfloat16* w3cal   = bb + 1441792;       // 256*512
    __hip_bfloat16* act_dd  = bb + 1572864;       // 2048*512
    __hip_bfloat16* act_cal = bb + 2621440;       // 2048*512
    __hip_bfloat16* act2b   = bb + 3670016;       // 2048*256
    __hip_bfloat16* act3b   = bb + 4194304;       // 2048*512

    prep_k<<<1536, 256, 0, stream>>>(cf, proto, dd_w1, dd_w2, cal_w1, cal_w2, cal_w3,
                                     ffm, fn, pn, pc, colsum, ffb, pcb,
                                     w1cat, w2dd, w2cal, w3cal);
    sim_addvec_k<<<514, 256, 0, stream>>>(ffb, pcb, fn, pn, ffm, dd_w1, dd_b1,
                                          out_drift, colsum, addvec);
    gemm1ln_k<<<128, 256, 0, stream>>>(pcb, w1cat, addvec, cal_b1,
                                       dd_g1, dd_be1, cal_g1, cal_be1,
                                       act_dd, act_cal);
    gemm2_k<<<384, 256, 0, stream>>>(act_dd, act_cal, w2dd, w2cal, dd_b2, cal_b2,
                                     act2b, act3b);
    gemm3_conf_k<<<640, 256, 0, stream>>>(act3b, w3cal, cal_b3, act2b, dd_w3, dd_b3,
                                          colsum, delta, strength, out_is);
    finalize_k<<<PP, 256, 0, stream>>>(pc, delta, strength, colsum, proto, out_cal);
}

// Round 3
// 413.211 us; speedup vs baseline: 1.0225x; 1.0225x over previous
//
#include <hip/hip_runtime.h>
#include <hip/hip_bf16.h>
#include <math.h>

#define BB 1024
#define TT 64
#define DD 256
#define PP 2048
#define HH 512

typedef __attribute__((ext_vector_type(8))) short short8;
typedef __attribute__((ext_vector_type(4))) short short4v;
typedef __attribute__((ext_vector_type(4))) float f32x4;

__device__ __forceinline__ float4 f4add(float4 a, float4 b) {
    return make_float4(a.x + b.x, a.y + b.y, a.z + b.z, a.w + b.w);
}

__device__ __forceinline__ void nt_store4(float* p, float4 v) {
    f32x4 t = {v.x, v.y, v.z, v.w};
    __builtin_nontemporal_store(t, (f32x4*)p);
}

__device__ __forceinline__ void nt_store1(float* p, float v) {
    __builtin_nontemporal_store(v, p);
}

// non-temporal read: bypass L1 allocation for streaming (read-once) data
__device__ __forceinline__ float4 nt_load4(const float* p) {
    f32x4 t = __builtin_nontemporal_load((const f32x4*)p);
    return make_float4(t.x, t.y, t.z, t.w);
}

__device__ __forceinline__ void store_bf16x4(__hip_bfloat16* dst, float4 m) {
    union { __hip_bfloat16 h[4]; short4v s; } u;
    u.h[0] = __float2bfloat16(m.x); u.h[1] = __float2bfloat16(m.y);
    u.h[2] = __float2bfloat16(m.z); u.h[3] = __float2bfloat16(m.w);
    *(short4v*)dst = u.s;
}

// ================ K1: prep — wave-per-row reductions, NT streaming loads ======
// blocks 0..767:    row reduce (4 rows/block, 1 wave per [64,256] row)
// blocks 768..1535: weight convert+transpose (4 elems/thread) + colsum zero
__global__ void prep_k(const float* __restrict__ cf, const float* __restrict__ proto,
                       const float* __restrict__ dd_w1, const float* __restrict__ dd_w2,
                       const float* __restrict__ cal_w1, const float* __restrict__ cal_w2,
                       const float* __restrict__ cal_w3,
                       float* __restrict__ ffm, float* __restrict__ fn,
                       float* __restrict__ pn, float* __restrict__ pc,
                       float* __restrict__ colsum,
                       __hip_bfloat16* __restrict__ ffb, __hip_bfloat16* __restrict__ pcb,
                       __hip_bfloat16* __restrict__ w1cat, __hip_bfloat16* __restrict__ w2dd,
                       __hip_bfloat16* __restrict__ w2cal, __hip_bfloat16* __restrict__ w3cal) {
    int b = blockIdx.x, tid = threadIdx.x;
    if (b < 768) {                          // 4 rows per block, wave w owns row 4b+w
        int wv = tid >> 6, lane = tid & 63;
        int row = (b << 2) + wv;            // 0..3071 (0..1023 cf, 1024..3071 proto)
        const float* base = (row < 1024) ? cf + (size_t)row * TT * DD
                                         : proto + (size_t)(row - 1024) * TT * DD;
        const float* p = base + (lane << 2);
        float4 acc = make_float4(0.f, 0.f, 0.f, 0.f);
        float4 v[16];
        #pragma unroll
        for (int tb = 0; tb < TT; tb += 16) {
            #pragma unroll
            for (int i = 0; i < 16; ++i)
                v[i] = nt_load4(p + (size_t)(tb + i) * DD);
            #pragma unroll
            for (int i = 0; i < 8; ++i) v[i] = f4add(v[i], v[i + 8]);
            #pragma unroll
            for (int i = 0; i < 4; ++i) v[i] = f4add(v[i], v[i + 4]);
            acc = f4add(acc, f4add(f4add(v[0], v[1]), f4add(v[2], v[3])));
        }
        float4 m = make_float4(acc.x * (1.f / TT), acc.y * (1.f / TT),
                               acc.z * (1.f / TT), acc.w * (1.f / TT));
        if (row < 1024) {
            *(float4*)(ffm + (size_t)row * DD + (lane << 2)) = m;
            store_bf16x4(ffb + (size_t)row * DD + (lane << 2), m);
        } else {
            int r = row - 1024;
            *(float4*)(pc + (size_t)r * DD + (lane << 2)) = m;
            store_bf16x4(pcb + (size_t)r * DD + (lane << 2), m);
        }
        float q = m.x * m.x + m.y * m.y + m.z * m.z + m.w * m.w;
        #pragma unroll
        for (int o = 32; o > 0; o >>= 1) q += __shfl_xor(q, o, 64);
        if (lane == 0) {
            float nv = fmaxf(sqrtf(q), 1e-8f);
            if (row < 1024) fn[row] = nv; else pn[row - 1024] = nv;
        }
    } else {                                // weight convert+transpose, 4 elems/thread
        int bb = b - 768;
        if (bb < 8) colsum[bb * 256 + tid] = 0.f;
        #pragma unroll
        for (int i2 = 0; i2 < 4; ++i2) {
            int idx = bb * 1024 + i2 * 256 + tid;
            if (idx < 262144) {               // w1cat: dd_w1 | cal_w1, K=256 N=512 each
                int half = idx >> 17;
                int i = idx & 131071;
                int n = i & 511, k = i >> 9;
                const float* src = half ? cal_w1 : dd_w1;
                float x = __builtin_nontemporal_load(src + (size_t)k * 512 + n);
                w1cat[(size_t)(half * 512 + n) * 256 + k] = __float2bfloat16(x);
            } else if (idx < 393216) {        // w2dd: K=512 N=256
                int i = idx - 262144;
                int n = i & 255, k = i >> 8;
                float x = __builtin_nontemporal_load(dd_w2 + (size_t)k * 256 + n);
                w2dd[(size_t)n * 512 + k] = __float2bfloat16(x);
            } else if (idx < 655360) {        // w2cal: K=512 N=512
                int i = idx - 393216;
                int n = i & 511, k = i >> 9;
                float x = __builtin_nontemporal_load(cal_w2 + (size_t)k * 512 + n);
                w2cal[(size_t)n * 512 + k] = __float2bfloat16(x);
            } else {                          // w3cal: K=512 N=256
                int i = idx - 655360;
                int n = i & 255, k = i >> 8;
                float x = __builtin_nontemporal_load(cal_w3 + (size_t)k * 256 + n);
                w3cal[(size_t)n * 512 + k] = __float2bfloat16(x);
            }
        }
    }
}

// ================ K2: sim MFMA + addvec, role by blockIdx =====================
__global__ void sim_addvec_k(const __hip_bfloat16* __restrict__ A,
                             const __hip_bfloat16* __restrict__ Bt,
                             const float* __restrict__ fn, const float* __restrict__ pn,
                             const float* __restrict__ ffm,
                             const float* __restrict__ dd_w1, const float* __restrict__ dd_b1,
                             float* __restrict__ drift, float* __restrict__ colsum,
                             float* __restrict__ addvec) {
    if (blockIdx.x >= 512) {              // addvec role: 2 blocks x 256 j's
        __shared__ float gmk[256];
        int tid = threadIdx.x;
        const float* f = ffm + tid;
        float a0 = 0.f, a1 = 0.f, a2 = 0.f, a3 = 0.f, a4 = 0.f, a5 = 0.f, a6 = 0.f, a7 = 0.f;
        #pragma unroll 4
        for (int b = 0; b < 1024; b += 8) {
            a0 += f[(b + 0) << 8]; a1 += f[(b + 1) << 8];
            a2 += f[(b + 2) << 8]; a3 += f[(b + 3) << 8];
            a4 += f[(b + 4) << 8]; a5 += f[(b + 5) << 8];
            a6 += f[(b + 6) << 8]; a7 += f[(b + 7) << 8];
        }
        gmk[tid] = (((a0 + a1) + (a2 + a3)) + ((a4 + a5) + (a6 + a7))) * (1.f / BB);
        __syncthreads();
        int j = (blockIdx.x - 512) * 256 + tid;
        float s = dd_b1[j];
        #pragma unroll 8
        for (int k = 0; k < 256; ++k) s = fmaf(gmk[k], dd_w1[(size_t)(256 + k) * 512 + j], s);
        addvec[j] = s;
        return;
    }
    int wid = (blockIdx.x << 2) + (threadIdx.x >> 6);   // 0..2047
    int lane = threadIdx.x & 63;
    int mw = wid >> 6, nw = wid & 63;
    int m0 = mw << 5, n0 = nw << 5;
    int lr = lane & 15, quad = lane >> 4;
    const __hip_bfloat16* pa0 = A + (size_t)(m0 + lr) * DD + quad * 8;
    const __hip_bfloat16* pa1 = pa0 + 16 * DD;
    const __hip_bfloat16* pb0 = Bt + (size_t)(n0 + lr) * DD + quad * 8;
    const __hip_bfloat16* pb1 = pb0 + 16 * DD;
    f32x4 acc00 = {0,0,0,0}, acc01 = {0,0,0,0}, acc10 = {0,0,0,0}, acc11 = {0,0,0,0};
    #pragma unroll
    for (int k = 0; k < DD; k += 32) {
        short8 a0 = *(const short8*)(pa0 + k);
        short8 a1 = *(const short8*)(pa1 + k);
        short8 b0 = *(const short8*)(pb0 + k);
        short8 b1 = *(const short8*)(pb1 + k);
        acc00 = __builtin_amdgcn_mfma_f32_16x16x32_bf16(a0, b0, acc00, 0, 0, 0);
        acc01 = __builtin_amdgcn_mfma_f32_16x16x32_bf16(a0, b1, acc01, 0, 0, 0);
        acc10 = __builtin_amdgcn_mfma_f32_16x16x32_bf16(a1, b0, acc10, 0, 0, 0);
        acc11 = __builtin_amdgcn_mfma_f32_16x16x32_bf16(a1, b1, acc11, 0, 0, 0);
    }
    int col0 = n0 + lr, col1 = col0 + 16;
    float ip0 = 1.f / pn[col0], ip1 = 1.f / pn[col1];
    float cs0 = 0.f, cs1 = 0.f;
    #pragma unroll
    for (int r = 0; r < 4; ++r) {
        int row0 = m0 + quad * 4 + r;
        int row1 = row0 + 16;
        float if0 = 1.f / fn[row0];
        float if1 = 1.f / fn[row1];
        float d00 = 1.f - acc00[r] * if0 * ip0;
        float d01 = 1.f - acc01[r] * if0 * ip1;
        float d10 = 1.f - acc10[r] * if1 * ip0;
        float d11 = 1.f - acc11[r] * if1 * ip1;
        nt_store1(&drift[(size_t)row0 * PP + col0], d00);
        nt_store1(&drift[(size_t)row0 * PP + col1], d01);
        nt_store1(&drift[(size_t)row1 * PP + col0], d10);
        nt_store1(&drift[(size_t)row1 * PP + col1], d11);
        cs0 += d00 + d10;
        cs1 += d01 + d11;
    }
    cs0 += __shfl_xor(cs0, 16, 64); cs0 += __shfl_xor(cs0, 32, 64);
    cs1 += __shfl_xor(cs1, 16, 64); cs1 += __shfl_xor(cs1, 32, 64);
    if (quad == 0) {
        atomicAdd(&colsum[col0], cs0);
        atomicAdd(&colsum[col1], cs1);
    }
}

// ================ K3: fused layer-1 GEMM + LayerNorm + ReLU -> bf16 ===========
__global__ void gemm1ln_k(const __hip_bfloat16* __restrict__ pcb,
                          const __hip_bfloat16* __restrict__ w1cat,
                          const float* __restrict__ addvec, const float* __restrict__ cal_b1,
                          const float* __restrict__ gdd, const float* __restrict__ bedd,
                          const float* __restrict__ gcal, const float* __restrict__ becal,
                          __hip_bfloat16* __restrict__ Ydd, __hip_bfloat16* __restrict__ Ycal) {
    __shared__ float lds_s[4][32];
    __shared__ float lds_q[4][32];
    int h = blockIdx.x >> 6;                 // 0: dd, 1: cal
    int r0 = (blockIdx.x & 63) << 5;         // row base
    int wv = threadIdx.x >> 6;               // wave 0..3
    int lane = threadIdx.x & 63;
    int lr = lane & 15, quad = lane >> 4;
    const float* bias = h ? cal_b1 : addvec;
    const float* g    = h ? gcal : gdd;
    const float* be   = h ? becal : bedd;
    __hip_bfloat16* Y = h ? Ycal : Ydd;

    const __hip_bfloat16* pa0 = pcb + (size_t)(r0 + lr) * DD + quad * 8;
    const __hip_bfloat16* pa1 = pa0 + 16 * DD;

    f32x4 a00[4], a01[4], a10[4], a11[4];
    float bi0[4], bi1[4];
    #pragma unroll
    for (int t = 0; t < 4; ++t) {
        int n0g = h * 512 + wv * 128 + t * 32;      // col in w1cat [1024][256]
        const __hip_bfloat16* pb0 = w1cat + (size_t)(n0g + lr) * DD + quad * 8;
        const __hip_bfloat16* pb1 = pb0 + 16 * DD;
        f32x4 c00 = {0,0,0,0}, c01 = {0,0,0,0}, c10 = {0,0,0,0}, c11 = {0,0,0,0};
        #pragma unroll
        for (int k = 0; k < DD; k += 32) {
            short8 av0 = *(const short8*)(pa0 + k);
            short8 av1 = *(const short8*)(pa1 + k);
            short8 bv0 = *(const short8*)(pb0 + k);
            short8 bv1 = *(const short8*)(pb1 + k);
            c00 = __builtin_amdgcn_mfma_f32_16x16x32_bf16(av0, bv0, c00, 0, 0, 0);
            c01 = __builtin_amdgcn_mfma_f32_16x16x32_bf16(av0, bv1, c01, 0, 0, 0);
            c10 = __builtin_amdgcn_mfma_f32_16x16x32_bf16(av1, bv0, c10, 0, 0, 0);
            c11 = __builtin_amdgcn_mfma_f32_16x16x32_bf16(av1, bv1, c11, 0, 0, 0);
        }
        a00[t] = c00; a01[t] = c01; a10[t] = c10; a11[t] = c11;
        int cl0 = wv * 128 + t * 32 + lr;           // col within half (0..511)
        bi0[t] = bias[cl0];
        bi1[t] = bias[cl0 + 16];
    }

    float ps_lo[4] = {0,0,0,0}, pq_lo[4] = {0,0,0,0};
    float ps_hi[4] = {0,0,0,0}, pq_hi[4] = {0,0,0,0};
    #pragma unroll
    for (int t = 0; t < 4; ++t) {
        #pragma unroll
        for (int r = 0; r < 4; ++r) {
            float v00 = a00[t][r] + bi0[t];
            float v01 = a01[t][r] + bi1[t];
            float v10 = a10[t][r] + bi0[t];
            float v11 = a11[t][r] + bi1[t];
            a00[t][r] = v00; a01[t][r] = v01; a10[t][r] = v10; a11[t][r] = v11;
            ps_lo[r] += v00 + v01;  pq_lo[r] += v00 * v00 + v01 * v01;
            ps_hi[r] += v10 + v11;  pq_hi[r] += v10 * v10 + v11 * v11;
        }
    }
    #pragma unroll
    for (int mset = 1; mset < 16; mset <<= 1) {
        #pragma unroll
        for (int r = 0; r < 4; ++r) {
            ps_lo[r] += __shfl_xor(ps_lo[r], mset, 64);
            pq_lo[r] += __shfl_xor(pq_lo[r], mset, 64);
            ps_hi[r] += __shfl_xor(ps_hi[r], mset, 64);
            pq_hi[r] += __shfl_xor(pq_hi[r], mset, 64);
        }
    }
    if (lr < 8) {
        int rr = quad * 4 + (lr & 3) + ((lr >> 2) << 4);
        lds_s[wv][rr] = (lr >= 4) ? ps_hi[lr & 3] : ps_lo[lr & 3];
        lds_q[wv][rr] = (lr >= 4) ? pq_hi[lr & 3] : pq_lo[lr & 3];
    }
    __syncthreads();

    float mu_lo[4], rs_lo[4], mu_hi[4], rs_hi[4];
    #pragma unroll
    for (int r = 0; r < 4; ++r) {
        int rl = quad * 4 + r;
        float s = lds_s[0][rl] + lds_s[1][rl] + lds_s[2][rl] + lds_s[3][rl];
        float q = lds_q[0][rl] + lds_q[1][rl] + lds_q[2][rl] + lds_q[3][rl];
        float mu = s * (1.f / HH);
        float var = fmaxf(q * (1.f / HH) - mu * mu, 0.f);
        mu_lo[r] = mu; rs_lo[r] = rsqrtf(var + 1e-5f);
        int rh = rl + 16;
        s = lds_s[0][rh] + lds_s[1][rh] + lds_s[2][rh] + lds_s[3][rh];
        q = lds_q[0][rh] + lds_q[1][rh] + lds_q[2][rh] + lds_q[3][rh];
        mu = s * (1.f / HH);
        var = fmaxf(q * (1.f / HH) - mu * mu, 0.f);
        mu_hi[r] = mu; rs_hi[r] = rsqrtf(var + 1e-5f);
    }

    #pragma unroll
    for (int t = 0; t < 4; ++t) {
        int c0 = wv * 128 + t * 32 + lr, c1 = c0 + 16;
        float g0 = g[c0], g1 = g[c1], b0 = be[c0], b1 = be[c1];
        #pragma unroll
        for (int r = 0; r < 4; ++r) {
            int row = r0 + quad * 4 + r;
            float y00 = fmaxf((a00[t][r] - mu_lo[r]) * rs_lo[r] * g0 + b0, 0.f);
            float y01 = fmaxf((a01[t][r] - mu_lo[r]) * rs_lo[r] * g1 + b1, 0.f);
            float y10 = fmaxf((a10[t][r] - mu_hi[r]) * rs_hi[r] * g0 + b0, 0.f);
            float y11 = fmaxf((a11[t][r] - mu_hi[r]) * rs_hi[r] * g1 + b1, 0.f);
            Y[(size_t)row * HH + c0]        = __float2bfloat16(y00);
            Y[(size_t)row * HH + c1]        = __float2bfloat16(y01);
            Y[(size_t)(row + 16) * HH + c0] = __float2bfloat16(y10);
            Y[(size_t)(row + 16) * HH + c1] = __float2bfloat16(y11);
        }
    }
}

// ================ 32x32 MFMA tile device function ============================
template <int K, int OUT_BF16, int RELU>
__device__ __forceinline__ void gemm_tile(const __hip_bfloat16* __restrict__ A,
                                          const __hip_bfloat16* __restrict__ Bt,
                                          const float* __restrict__ bias0,
                                          const float* __restrict__ bias1, int split,
                                          void* __restrict__ Cout, int N, int lognt,
                                          int wid, int lane) {
    int mw = wid >> lognt, nw = wid & ((1 << lognt) - 1);
    int m0 = mw << 5, n0 = nw << 5;
    int lr = lane & 15, quad = lane >> 4;
    const __hip_bfloat16* pa0 = A + (size_t)(m0 + lr) * K + quad * 8;
    const __hip_bfloat16* pa1 = pa0 + 16 * K;
    const __hip_bfloat16* pb0 = Bt + (size_t)(n0 + lr) * K + quad * 8;
    const __hip_bfloat16* pb1 = pb0 + 16 * K;
    f32x4 acc00 = {0,0,0,0}, acc01 = {0,0,0,0}, acc10 = {0,0,0,0}, acc11 = {0,0,0,0};
    #pragma unroll
    for (int k = 0; k < K; k += 32) {
        short8 a0 = *(const short8*)(pa0 + k);
        short8 a1 = *(const short8*)(pa1 + k);
        short8 b0 = *(const short8*)(pb0 + k);
        short8 b1 = *(const short8*)(pb1 + k);
        acc00 = __builtin_amdgcn_mfma_f32_16x16x32_bf16(a0, b0, acc00, 0, 0, 0);
        acc01 = __builtin_amdgcn_mfma_f32_16x16x32_bf16(a0, b1, acc01, 0, 0, 0);
        acc10 = __builtin_amdgcn_mfma_f32_16x16x32_bf16(a1, b0, acc10, 0, 0, 0);
        acc11 = __builtin_amdgcn_mfma_f32_16x16x32_bf16(a1, b1, acc11, 0, 0, 0);
    }
    int col0 = n0 + lr, col1 = col0 + 16;
    float bi0 = (col0 < split) ? bias0[col0] : bias1[col0 - split];
    float bi1 = (col1 < split) ? bias0[col1] : bias1[col1 - split];
    #pragma unroll
    for (int r = 0; r < 4; ++r) {
        int row0 = m0 + quad * 4 + r;
        int row1 = row0 + 16;
        float v00 = acc00[r] + bi0, v01 = acc01[r] + bi1;
        float v10 = acc10[r] + bi0, v11 = acc11[r] + bi1;
        if (RELU) {
            v00 = fmaxf(v00, 0.f); v01 = fmaxf(v01, 0.f);
            v10 = fmaxf(v10, 0.f); v11 = fmaxf(v11, 0.f);
        }
        if (OUT_BF16) {
            __hip_bfloat16* C = (__hip_bfloat16*)Cout;
            C[(size_t)row0 * N + col0] = __float2bfloat16(v00);
            C[(size_t)row0 * N + col1] = __float2bfloat16(v01);
            C[(size_t)row1 * N + col0] = __float2bfloat16(v10);
            C[(size_t)row1 * N + col1] = __float2bfloat16(v11);
        } else {
            float* C = (float*)Cout;
            C[(size_t)row0 * N + col0] = v00;
            C[(size_t)row0 * N + col1] = v01;
            C[(size_t)row1 * N + col0] = v10;
            C[(size_t)row1 * N + col1] = v11;
        }
    }
}

// ================ K4: dd2 + cal2 GEMMs, role by blockIdx ======================
__global__ void gemm2_k(const __hip_bfloat16* __restrict__ act_dd,
                        const __hip_bfloat16* __restrict__ act_cal,
                        const __hip_bfloat16* __restrict__ w2dd,
                        const __hip_bfloat16* __restrict__ w2cal,
                        const float* __restrict__ dd_b2, const float* __restrict__ cal_b2,
                        __hip_bfloat16* __restrict__ act2b, __hip_bfloat16* __restrict__ act3b) {
    int lane = threadIdx.x & 63;
    if (blockIdx.x < 128) {   // dd2: [2048,512]@[512,256] -> act2b
        int wid = (blockIdx.x << 2) + (threadIdx.x >> 6);
        gemm_tile<512, 1, 1>(act_dd, w2dd, dd_b2, dd_b2, 1 << 30, act2b, 256, 3, wid, lane);
    } else {                  // cal2: [2048,512]@[512,512] -> act3b
        int wid = ((blockIdx.x - 128) << 2) + (threadIdx.x >> 6);
        gemm_tile<512, 1, 1>(act_cal, w2cal, cal_b2, cal_b2, 1 << 30, act3b, 512, 4, wid, lane);
    }
}

// ================ K5: cal3 GEMM + conf/sigmoid/is_drifted =====================
__global__ void gemm3_conf_k(const __hip_bfloat16* __restrict__ act3b,
                             const __hip_bfloat16* __restrict__ w3cal,
                             const float* __restrict__ cal_b3,
                             const __hip_bfloat16* __restrict__ act2b,
                             const float* __restrict__ dd_w3, const float* __restrict__ dd_b3,
                             const float* __restrict__ colsum,
                             float* __restrict__ delta, float* __restrict__ strength,
                             float* __restrict__ out_is) {
    if (blockIdx.x < 128) {   // cal3: [2048,512]@[512,256] -> delta fp32
        int wid = (blockIdx.x << 2) + (threadIdx.x >> 6);
        gemm_tile<512, 0, 0>(act3b, w3cal, cal_b3, cal_b3, 1 << 30, delta, 256, 3,
                             wid, threadIdx.x & 63);
        return;
    }
    // conf role: one wave per p, blocks 128..639
    int p = ((blockIdx.x - 128) << 2) + (threadIdx.x >> 6);   // 0..2047
    int lane = threadIdx.x & 63;
    const __hip_bfloat16* row = act2b + (size_t)p * 256 + lane * 4;
    float s = 0.f;
    #pragma unroll
    for (int j = 0; j < 4; ++j)
        s += __bfloat162float(row[j]) * dd_w3[lane * 4 + j];
    #pragma unroll
    for (int o = 32; o > 0; o >>= 1) s += __shfl_down(s, o, 64);
    if (lane == 0) {
        float conf = 1.f / (1.f + expf(-(s + dd_b3[0])));
        strength[p] = fminf(fmaxf(0.1f * conf, 0.f), 0.5f);
        out_is[p] = (colsum[p] * (1.f / BB) > 0.3f) ? 1.f : 0.f;
    }
}

// ================ K6: write calibrated [P,T,D], NT in / NT out ================
__global__ void finalize_k(const float* __restrict__ pc, const float* __restrict__ delta,
                           const float* __restrict__ strength, const float* __restrict__ colsum,
                           const float* __restrict__ proto, float* __restrict__ out) {
    int p = blockIdx.x;
    int d4 = (threadIdx.x & 63) << 2;
    int t0 = threadIdx.x >> 6;
    bool dr = colsum[p] * (1.f / BB) > 0.3f;
    float* o = out + (size_t)p * TT * DD;
    if (dr) {
        float s = strength[p];
        float4 pcv = *(const float4*)(pc + (size_t)p * DD + d4);
        float4 dv  = *(const float4*)(delta + (size_t)p * DD + d4);
        float4 nc = make_float4(fmaf(s, dv.x, pcv.x), fmaf(s, dv.y, pcv.y),
                                fmaf(s, dv.z, pcv.z), fmaf(s, dv.w, pcv.w));
        #pragma unroll
        for (int t = t0; t < TT; t += 4)
            nt_store4(o + t * DD + d4, nc);
    } else {
        const float* pr = proto + (size_t)p * TT * DD;
        #pragma unroll
        for (int t = t0; t < TT; t += 4)
            nt_store4(o + t * DD + d4, nt_load4(pr + t * DD + d4));
    }
}

extern "C" void kernel_launch(void* const* d_in, const int* in_sizes, int n_in,
                              void* d_out, int out_size, void* d_ws, size_t ws_size,
                              hipStream_t stream) {
    const float* cf     = (const float*)d_in[0];
    const float* proto  = (const float*)d_in[1];
    const float* dd_w1  = (const float*)d_in[2];
    const float* dd_b1  = (const float*)d_in[3];
    const float* dd_g1  = (const float*)d_in[4];
    const float* dd_be1 = (const float*)d_in[5];
    const float* dd_w2  = (const float*)d_in[6];
    const float* dd_b2  = (const float*)d_in[7];
    const float* dd_w3  = (const float*)d_in[8];
    const float* dd_b3  = (const float*)d_in[9];
    const float* cal_w1 = (const float*)d_in[10];
    const float* cal_b1 = (const float*)d_in[11];
    const float* cal_g1 = (const float*)d_in[12];
    const float* cal_be1= (const float*)d_in[13];
    const float* cal_w2 = (const float*)d_in[14];
    const float* cal_b2 = (const float*)d_in[15];
    const float* cal_w3 = (const float*)d_in[16];
    const float* cal_b3 = (const float*)d_in[17];

    float* out_cal   = (float*)d_out;
    float* out_drift = out_cal + (size_t)PP * TT * DD;
    float* out_is    = out_drift + (size_t)BB * PP;

    float* w = (float*)d_ws;
    float* colsum   = w;               // 2048 (zeroed inside prep_k)
    float* addvec   = w + 4096;        // 512
    float* fn       = w + 4608;        // 1024
    float* pn       = w + 5632;        // 2048
    float* strength = w + 7680;        // 2048
    float* pc       = w + 9728;        // 2048*256
    float* ffm      = w + 534016;      // 1024*256 fp32 (gmean source)
    float* delta    = w + 2631168;     // 2048*256
    __hip_bfloat16* bb = (__hip_bfloat16*)(w + 3155456);
    __hip_bfloat16* ffb     = bb;                 // 1024*256
    __hip_bfloat16* pcb     = bb + 262144;        // 2048*256
    __hip_bfloat16* w1cat   = bb + 786432;        // 1024*256
    __hip_bfloat16* w2dd    = bb + 1048576;       // 256*512
    __hip_bfloat16* w2cal   = bb + 1179648;       // 512*512
    __hip_bfloat16* w3cal   = bb + 1441792;       // 256*512
    __hip_bfloat16* act_dd  = bb + 1572864;       // 2048*512
    __hip_bfloat16* act_cal = bb + 2621440;       // 2048*512
    __hip_bfloat16* act2b   = bb + 3670016;       // 2048*256
    __hip_bfloat16* act3b   = bb + 4194304;       // 2048*512

    prep_k<<<1536, 256, 0, stream>>>(cf, proto, dd_w1, dd_w2, cal_w1, cal_w2, cal_w3,
                                     ffm, fn, pn, pc, colsum, ffb, pcb,
                                     w1cat, w2dd, w2cal, w3cal);
    sim_addvec_k<<<514, 256, 0, stream>>>(ffb, pcb, fn, pn, ffm, dd_w1, dd_b1,
                                          out_drift, colsum, addvec);
    gemm1ln_k<<<128, 256, 0, stream>>>(pcb, w1cat, addvec, cal_b1,
                                       dd_g1, dd_be1, cal_g1, cal_be1,
                                       act_dd, act_cal);
    gemm2_k<<<384, 256, 0, stream>>>(act_dd, act_cal, w2dd, w2cal, dd_b2, cal_b2,
                                     act2b, act3b);
    gemm3_conf_k<<<640, 256, 0, stream>>>(act3b, w3cal, cal_b3, act2b, dd_w3, dd_b3,
                                          colsum, delta, strength, out_is);
    finalize_k<<<PP, 256, 0, stream>>>(pc, delta, strength, colsum, proto, out_cal);
}

// Round 4
// 399.728 us; speedup vs baseline: 1.0570x; 1.0337x over previous
//
#include <hip/hip_runtime.h>
#include <hip/hip_bf16.h>
#include <math.h>

#define BB 1024
#define TT 64
#define DD 256
#define PP 2048
#define HH 512

typedef __attribute__((ext_vector_type(8))) short short8;
typedef __attribute__((ext_vector_type(4))) short short4v;
typedef __attribute__((ext_vector_type(4))) float f32x4;

__device__ __forceinline__ float4 f4add(float4 a, float4 b) {
    return make_float4(a.x + b.x, a.y + b.y, a.z + b.z, a.w + b.w);
}

__device__ __forceinline__ void nt_store4(float* p, float4 v) {
    f32x4 t = {v.x, v.y, v.z, v.w};
    __builtin_nontemporal_store(t, (f32x4*)p);
}

__device__ __forceinline__ void nt_store1(float* p, float v) {
    __builtin_nontemporal_store(v, p);
}

// non-temporal read: bypass L1 allocation for streaming (read-once) data
__device__ __forceinline__ float4 nt_load4(const float* p) {
    f32x4 t = __builtin_nontemporal_load((const f32x4*)p);
    return make_float4(t.x, t.y, t.z, t.w);
}

__device__ __forceinline__ void store_bf16x4(__hip_bfloat16* dst, float4 m) {
    union { __hip_bfloat16 h[4]; short4v s; } u;
    u.h[0] = __float2bfloat16(m.x); u.h[1] = __float2bfloat16(m.y);
    u.h[2] = __float2bfloat16(m.z); u.h[3] = __float2bfloat16(m.w);
    *(short4v*)dst = u.s;
}

// ================ K1: prep — wave-per-row reductions, NT streaming loads ======
// blocks 0..767:    row reduce (4 rows/block, 1 wave per [64,256] row)
// blocks 768..1535: weight convert+transpose (4 elems/thread) + colsum zero
__global__ void prep_k(const float* __restrict__ cf, const float* __restrict__ proto,
                       const float* __restrict__ dd_w1, const float* __restrict__ dd_w2,
                       const float* __restrict__ cal_w1, const float* __restrict__ cal_w2,
                       const float* __restrict__ cal_w3,
                       float* __restrict__ ffm, float* __restrict__ fn,
                       float* __restrict__ pn, float* __restrict__ pc,
                       float* __restrict__ colsum,
                       __hip_bfloat16* __restrict__ ffb, __hip_bfloat16* __restrict__ pcb,
                       __hip_bfloat16* __restrict__ w1cat, __hip_bfloat16* __restrict__ w2dd,
                       __hip_bfloat16* __restrict__ w2cal, __hip_bfloat16* __restrict__ w3cal) {
    int b = blockIdx.x, tid = threadIdx.x;
    if (b < 768) {                          // 4 rows per block, wave w owns row 4b+w
        int wv = tid >> 6, lane = tid & 63;
        int row = (b << 2) + wv;            // 0..3071 (0..1023 cf, 1024..3071 proto)
        const float* base = (row < 1024) ? cf + (size_t)row * TT * DD
                                         : proto + (size_t)(row - 1024) * TT * DD;
        const float* p = base + (lane << 2);
        float4 acc = make_float4(0.f, 0.f, 0.f, 0.f);
        float4 v[16];
        #pragma unroll
        for (int tb = 0; tb < TT; tb += 16) {
            #pragma unroll
            for (int i = 0; i < 16; ++i)
                v[i] = nt_load4(p + (size_t)(tb + i) * DD);
            #pragma unroll
            for (int i = 0; i < 8; ++i) v[i] = f4add(v[i], v[i + 8]);
            #pragma unroll
            for (int i = 0; i < 4; ++i) v[i] = f4add(v[i], v[i + 4]);
            acc = f4add(acc, f4add(f4add(v[0], v[1]), f4add(v[2], v[3])));
        }
        float4 m = make_float4(acc.x * (1.f / TT), acc.y * (1.f / TT),
                               acc.z * (1.f / TT), acc.w * (1.f / TT));
        if (row < 1024) {
            *(float4*)(ffm + (size_t)row * DD + (lane << 2)) = m;
            store_bf16x4(ffb + (size_t)row * DD + (lane << 2), m);
        } else {
            int r = row - 1024;
            *(float4*)(pc + (size_t)r * DD + (lane << 2)) = m;
            store_bf16x4(pcb + (size_t)r * DD + (lane << 2), m);
        }
        float q = m.x * m.x + m.y * m.y + m.z * m.z + m.w * m.w;
        #pragma unroll
        for (int o = 32; o > 0; o >>= 1) q += __shfl_xor(q, o, 64);
        if (lane == 0) {
            float nv = fmaxf(sqrtf(q), 1e-8f);
            if (row < 1024) fn[row] = nv; else pn[row - 1024] = nv;
        }
    } else {                                // weight convert+transpose, 4 elems/thread
        int bb = b - 768;
        if (bb < 8) colsum[bb * 256 + tid] = 0.f;
        #pragma unroll
        for (int i2 = 0; i2 < 4; ++i2) {
            int idx = bb * 1024 + i2 * 256 + tid;
            if (idx < 262144) {               // w1cat: dd_w1 | cal_w1, K=256 N=512 each
                int half = idx >> 17;
                int i = idx & 131071;
                int n = i & 511, k = i >> 9;
                const float* src = half ? cal_w1 : dd_w1;
                float x = __builtin_nontemporal_load(src + (size_t)k * 512 + n);
                w1cat[(size_t)(half * 512 + n) * 256 + k] = __float2bfloat16(x);
            } else if (idx < 393216) {        // w2dd: K=512 N=256
                int i = idx - 262144;
                int n = i & 255, k = i >> 8;
                float x = __builtin_nontemporal_load(dd_w2 + (size_t)k * 256 + n);
                w2dd[(size_t)n * 512 + k] = __float2bfloat16(x);
            } else if (idx < 655360) {        // w2cal: K=512 N=512
                int i = idx - 393216;
                int n = i & 511, k = i >> 9;
                float x = __builtin_nontemporal_load(cal_w2 + (size_t)k * 512 + n);
                w2cal[(size_t)n * 512 + k] = __float2bfloat16(x);
            } else {                          // w3cal: K=512 N=256
                int i = idx - 655360;
                int n = i & 255, k = i >> 8;
                float x = __builtin_nontemporal_load(cal_w3 + (size_t)k * 256 + n);
                w3cal[(size_t)n * 512 + k] = __float2bfloat16(x);
            }
        }
    }
}

// ================ K2: sim MFMA + addvec, role by blockIdx =====================
__global__ void sim_addvec_k(const __hip_bfloat16* __restrict__ A,
                             const __hip_bfloat16* __restrict__ Bt,
                             const float* __restrict__ fn, const float* __restrict__ pn,
                             const float* __restrict__ ffm,
                             const float* __restrict__ dd_w1, const float* __restrict__ dd_b1,
                             float* __restrict__ drift, float* __restrict__ colsum,
                             float* __restrict__ addvec) {
    if (blockIdx.x >= 512) {              // addvec role: 2 blocks x 256 j's
        __shared__ float gmk[256];
        int tid = threadIdx.x;
        const float* f = ffm + tid;
        float a0 = 0.f, a1 = 0.f, a2 = 0.f, a3 = 0.f, a4 = 0.f, a5 = 0.f, a6 = 0.f, a7 = 0.f;
        #pragma unroll 4
        for (int b = 0; b < 1024; b += 8) {
            a0 += f[(b + 0) << 8]; a1 += f[(b + 1) << 8];
            a2 += f[(b + 2) << 8]; a3 += f[(b + 3) << 8];
            a4 += f[(b + 4) << 8]; a5 += f[(b + 5) << 8];
            a6 += f[(b + 6) << 8]; a7 += f[(b + 7) << 8];
        }
        gmk[tid] = (((a0 + a1) + (a2 + a3)) + ((a4 + a5) + (a6 + a7))) * (1.f / BB);
        __syncthreads();
        int j = (blockIdx.x - 512) * 256 + tid;
        float s = dd_b1[j];
        #pragma unroll 8
        for (int k = 0; k < 256; ++k) s = fmaf(gmk[k], dd_w1[(size_t)(256 + k) * 512 + j], s);
        addvec[j] = s;
        return;
    }
    int wid = (blockIdx.x << 2) + (threadIdx.x >> 6);   // 0..2047
    int lane = threadIdx.x & 63;
    int mw = wid >> 6, nw = wid & 63;
    int m0 = mw << 5, n0 = nw << 5;
    int lr = lane & 15, quad = lane >> 4;
    const __hip_bfloat16* pa0 = A + (size_t)(m0 + lr) * DD + quad * 8;
    const __hip_bfloat16* pa1 = pa0 + 16 * DD;
    const __hip_bfloat16* pb0 = Bt + (size_t)(n0 + lr) * DD + quad * 8;
    const __hip_bfloat16* pb1 = pb0 + 16 * DD;
    f32x4 acc00 = {0,0,0,0}, acc01 = {0,0,0,0}, acc10 = {0,0,0,0}, acc11 = {0,0,0,0};
    #pragma unroll
    for (int k = 0; k < DD; k += 32) {
        short8 a0 = *(const short8*)(pa0 + k);
        short8 a1 = *(const short8*)(pa1 + k);
        short8 b0 = *(const short8*)(pb0 + k);
        short8 b1 = *(const short8*)(pb1 + k);
        acc00 = __builtin_amdgcn_mfma_f32_16x16x32_bf16(a0, b0, acc00, 0, 0, 0);
        acc01 = __builtin_amdgcn_mfma_f32_16x16x32_bf16(a0, b1, acc01, 0, 0, 0);
        acc10 = __builtin_amdgcn_mfma_f32_16x16x32_bf16(a1, b0, acc10, 0, 0, 0);
        acc11 = __builtin_amdgcn_mfma_f32_16x16x32_bf16(a1, b1, acc11, 0, 0, 0);
    }
    int col0 = n0 + lr, col1 = col0 + 16;
    float ip0 = 1.f / pn[col0], ip1 = 1.f / pn[col1];
    float cs0 = 0.f, cs1 = 0.f;
    #pragma unroll
    for (int r = 0; r < 4; ++r) {
        int row0 = m0 + quad * 4 + r;
        int row1 = row0 + 16;
        float if0 = 1.f / fn[row0];
        float if1 = 1.f / fn[row1];
        float d00 = 1.f - acc00[r] * if0 * ip0;
        float d01 = 1.f - acc01[r] * if0 * ip1;
        float d10 = 1.f - acc10[r] * if1 * ip0;
        float d11 = 1.f - acc11[r] * if1 * ip1;
        nt_store1(&drift[(size_t)row0 * PP + col0], d00);
        nt_store1(&drift[(size_t)row0 * PP + col1], d01);
        nt_store1(&drift[(size_t)row1 * PP + col0], d10);
        nt_store1(&drift[(size_t)row1 * PP + col1], d11);
        cs0 += d00 + d10;
        cs1 += d01 + d11;
    }
    cs0 += __shfl_xor(cs0, 16, 64); cs0 += __shfl_xor(cs0, 32, 64);
    cs1 += __shfl_xor(cs1, 16, 64); cs1 += __shfl_xor(cs1, 32, 64);
    if (quad == 0) {
        atomicAdd(&colsum[col0], cs0);
        atomicAdd(&colsum[col1], cs1);
    }
}

// ================ K3: fully fused MLP (both nets), activations in LDS =========
// 128 blocks x 256 threads. h = bid&1 (0 dd, 1 cal); rows r0 = (bid>>1)*32.
// phase1: layer1 (K=256) + LN + ReLU -> act1 (LDS bf16, stride 520)
// phase2: layer2 (K=512) + ReLU     -> act2 (LDS bf16)
// phase3: dd: conf dot + sigmoid -> strength; cal: layer3 (K=512) -> delta fp32
#define LS 520   // LDS row stride in bf16 (1040 B): <=2-way bank aliasing
__global__ void __launch_bounds__(256)
mlp_k(const __hip_bfloat16* __restrict__ pcb,
      const __hip_bfloat16* __restrict__ w1cat,
      const float* __restrict__ addvec, const float* __restrict__ cal_b1,
      const float* __restrict__ gdd, const float* __restrict__ bedd,
      const float* __restrict__ gcal, const float* __restrict__ becal,
      const __hip_bfloat16* __restrict__ w2dd, const __hip_bfloat16* __restrict__ w2cal,
      const float* __restrict__ dd_b2, const float* __restrict__ cal_b2,
      const __hip_bfloat16* __restrict__ w3cal, const float* __restrict__ cal_b3,
      const float* __restrict__ dd_w3, const float* __restrict__ dd_b3,
      float* __restrict__ delta, float* __restrict__ strength) {
    __shared__ __hip_bfloat16 act1[32 * LS];
    __shared__ __hip_bfloat16 act2[32 * LS];
    __shared__ float lds_s[4][32];
    __shared__ float lds_q[4][32];

    int h  = blockIdx.x & 1;
    int r0 = (blockIdx.x >> 1) << 5;
    int wv = threadIdx.x >> 6;
    int lane = threadIdx.x & 63;
    int lr = lane & 15, quad = lane >> 4;

    const float* bias1 = h ? cal_b1 : addvec;
    const float* g  = h ? gcal : gdd;
    const float* be = h ? becal : bedd;

    // ---------------- phase 1: layer1 GEMM ----------------
    const __hip_bfloat16* pa0 = pcb + (size_t)(r0 + lr) * DD + quad * 8;
    const __hip_bfloat16* pa1 = pa0 + 16 * DD;
    f32x4 a00[4], a01[4], a10[4], a11[4];
    float bi0[4], bi1[4];
    #pragma unroll
    for (int t = 0; t < 4; ++t) {
        int n0g = h * 512 + wv * 128 + t * 32;      // row in w1cat [1024][256]
        const __hip_bfloat16* pb0 = w1cat + (size_t)(n0g + lr) * DD + quad * 8;
        const __hip_bfloat16* pb1 = pb0 + 16 * DD;
        f32x4 c00 = {0,0,0,0}, c01 = {0,0,0,0}, c10 = {0,0,0,0}, c11 = {0,0,0,0};
        #pragma unroll
        for (int k = 0; k < DD; k += 32) {
            short8 av0 = *(const short8*)(pa0 + k);
            short8 av1 = *(const short8*)(pa1 + k);
            short8 bv0 = *(const short8*)(pb0 + k);
            short8 bv1 = *(const short8*)(pb1 + k);
            c00 = __builtin_amdgcn_mfma_f32_16x16x32_bf16(av0, bv0, c00, 0, 0, 0);
            c01 = __builtin_amdgcn_mfma_f32_16x16x32_bf16(av0, bv1, c01, 0, 0, 0);
            c10 = __builtin_amdgcn_mfma_f32_16x16x32_bf16(av1, bv0, c10, 0, 0, 0);
            c11 = __builtin_amdgcn_mfma_f32_16x16x32_bf16(av1, bv1, c11, 0, 0, 0);
        }
        a00[t] = c00; a01[t] = c01; a10[t] = c10; a11[t] = c11;
        int cl0 = wv * 128 + t * 32 + lr;
        bi0[t] = bias1[cl0];
        bi1[t] = bias1[cl0 + 16];
    }
    // bias add + per-row partial sum/sumsq over this wave's 128 cols
    float ps_lo[4] = {0,0,0,0}, pq_lo[4] = {0,0,0,0};
    float ps_hi[4] = {0,0,0,0}, pq_hi[4] = {0,0,0,0};
    #pragma unroll
    for (int t = 0; t < 4; ++t) {
        #pragma unroll
        for (int r = 0; r < 4; ++r) {
            float v00 = a00[t][r] + bi0[t];
            float v01 = a01[t][r] + bi1[t];
            float v10 = a10[t][r] + bi0[t];
            float v11 = a11[t][r] + bi1[t];
            a00[t][r] = v00; a01[t][r] = v01; a10[t][r] = v10; a11[t][r] = v11;
            ps_lo[r] += v00 + v01;  pq_lo[r] += v00 * v00 + v01 * v01;
            ps_hi[r] += v10 + v11;  pq_hi[r] += v10 * v10 + v11 * v11;
        }
    }
    #pragma unroll
    for (int mset = 1; mset < 16; mset <<= 1) {
        #pragma unroll
        for (int r = 0; r < 4; ++r) {
            ps_lo[r] += __shfl_xor(ps_lo[r], mset, 64);
            pq_lo[r] += __shfl_xor(pq_lo[r], mset, 64);
            ps_hi[r] += __shfl_xor(ps_hi[r], mset, 64);
            pq_hi[r] += __shfl_xor(pq_hi[r], mset, 64);
        }
    }
    if (lr < 8) {
        int rr = quad * 4 + (lr & 3) + ((lr >> 2) << 4);
        lds_s[wv][rr] = (lr >= 4) ? ps_hi[lr & 3] : ps_lo[lr & 3];
        lds_q[wv][rr] = (lr >= 4) ? pq_hi[lr & 3] : pq_lo[lr & 3];
    }
    __syncthreads();

    float mu_lo[4], rs_lo[4], mu_hi[4], rs_hi[4];
    #pragma unroll
    for (int r = 0; r < 4; ++r) {
        int rl = quad * 4 + r;
        float s = lds_s[0][rl] + lds_s[1][rl] + lds_s[2][rl] + lds_s[3][rl];
        float q = lds_q[0][rl] + lds_q[1][rl] + lds_q[2][rl] + lds_q[3][rl];
        float mu = s * (1.f / HH);
        float var = fmaxf(q * (1.f / HH) - mu * mu, 0.f);
        mu_lo[r] = mu; rs_lo[r] = rsqrtf(var + 1e-5f);
        int rh = rl + 16;
        s = lds_s[0][rh] + lds_s[1][rh] + lds_s[2][rh] + lds_s[3][rh];
        q = lds_q[0][rh] + lds_q[1][rh] + lds_q[2][rh] + lds_q[3][rh];
        mu = s * (1.f / HH);
        var = fmaxf(q * (1.f / HH) - mu * mu, 0.f);
        mu_hi[r] = mu; rs_hi[r] = rsqrtf(var + 1e-5f);
    }
    // normalized + relu -> act1 (bf16 LDS)
    #pragma unroll
    for (int t = 0; t < 4; ++t) {
        int c0 = wv * 128 + t * 32 + lr, c1 = c0 + 16;
        float g0 = g[c0], g1 = g[c1], b0 = be[c0], b1 = be[c1];
        #pragma unroll
        for (int r = 0; r < 4; ++r) {
            int rl = quad * 4 + r, rh = rl + 16;
            act1[rl * LS + c0] = __float2bfloat16(fmaxf((a00[t][r] - mu_lo[r]) * rs_lo[r] * g0 + b0, 0.f));
            act1[rl * LS + c1] = __float2bfloat16(fmaxf((a01[t][r] - mu_lo[r]) * rs_lo[r] * g1 + b1, 0.f));
            act1[rh * LS + c0] = __float2bfloat16(fmaxf((a10[t][r] - mu_hi[r]) * rs_hi[r] * g0 + b0, 0.f));
            act1[rh * LS + c1] = __float2bfloat16(fmaxf((a11[t][r] - mu_hi[r]) * rs_hi[r] * g1 + b1, 0.f));
        }
    }
    __syncthreads();

    // ---------------- phase 2: layer2 GEMM (K=512) + ReLU -> act2 -------------
    {
        const __hip_bfloat16* w2 = h ? w2cal : w2dd;
        const float* b2 = h ? cal_b2 : dd_b2;
        int nt2 = h ? 4 : 2;                       // tiles per wave (N=512 / 256)
        #pragma unroll
        for (int tt = 0; tt < 4; ++tt) {
            if (tt < nt2) {
                int n0 = wv * (nt2 << 5) + (tt << 5);
                const __hip_bfloat16* pb0 = w2 + (size_t)(n0 + lr) * 512 + quad * 8;
                const __hip_bfloat16* pb1 = pb0 + 16 * 512;
                f32x4 c00 = {0,0,0,0}, c01 = {0,0,0,0}, c10 = {0,0,0,0}, c11 = {0,0,0,0};
                #pragma unroll
                for (int k = 0; k < 512; k += 32) {
                    short8 av0 = *(const short8*)&act1[lr * LS + quad * 8 + k];
                    short8 av1 = *(const short8*)&act1[(lr + 16) * LS + quad * 8 + k];
                    short8 bv0 = *(const short8*)(pb0 + k);
                    short8 bv1 = *(const short8*)(pb1 + k);
                    c00 = __builtin_amdgcn_mfma_f32_16x16x32_bf16(av0, bv0, c00, 0, 0, 0);
                    c01 = __builtin_amdgcn_mfma_f32_16x16x32_bf16(av0, bv1, c01, 0, 0, 0);
                    c10 = __builtin_amdgcn_mfma_f32_16x16x32_bf16(av1, bv0, c10, 0, 0, 0);
                    c11 = __builtin_amdgcn_mfma_f32_16x16x32_bf16(av1, bv1, c11, 0, 0, 0);
                }
                float bb0 = b2[n0 + lr], bb1 = b2[n0 + 16 + lr];
                #pragma unroll
                for (int r = 0; r < 4; ++r) {
                    int rl = quad * 4 + r, rh = rl + 16;
                    act2[rl * LS + n0 + lr]      = __float2bfloat16(fmaxf(c00[r] + bb0, 0.f));
                    act2[rl * LS + n0 + 16 + lr] = __float2bfloat16(fmaxf(c01[r] + bb1, 0.f));
                    act2[rh * LS + n0 + lr]      = __float2bfloat16(fmaxf(c10[r] + bb0, 0.f));
                    act2[rh * LS + n0 + 16 + lr] = __float2bfloat16(fmaxf(c11[r] + bb1, 0.f));
                }
            }
        }
    }
    __syncthreads();

    // ---------------- phase 3 ----------------
    if (h == 0) {
        // conf: row = tid>>3 (0..31), 8 threads per row over 256 cols
        int r = threadIdx.x >> 3, e = threadIdx.x & 7;
        float s = 0.f;
        #pragma unroll 8
        for (int c = 0; c < 32; ++c) {
            int cc = e * 32 + c;
            s += __bfloat162float(act2[r * LS + cc]) * dd_w3[cc];
        }
        s += __shfl_down(s, 4, 8);
        s += __shfl_down(s, 2, 8);
        s += __shfl_down(s, 1, 8);
        if (e == 0) {
            float conf = 1.f / (1.f + expf(-(s + dd_b3[0])));
            strength[r0 + r] = fminf(fmaxf(0.1f * conf, 0.f), 0.5f);
        }
    } else {
        // layer3: [32,512] @ w3cal^T[256,512] -> delta fp32 [32,256]
        #pragma unroll
        for (int tt = 0; tt < 2; ++tt) {
            int n0 = (wv << 6) + (tt << 5);
            const __hip_bfloat16* pb0 = w3cal + (size_t)(n0 + lr) * 512 + quad * 8;
            const __hip_bfloat16* pb1 = pb0 + 16 * 512;
            f32x4 c00 = {0,0,0,0}, c01 = {0,0,0,0}, c10 = {0,0,0,0}, c11 = {0,0,0,0};
            #pragma unroll
            for (int k = 0; k < 512; k += 32) {
                short8 av0 = *(const short8*)&act2[lr * LS + quad * 8 + k];
                short8 av1 = *(const short8*)&act2[(lr + 16) * LS + quad * 8 + k];
                short8 bv0 = *(const short8*)(pb0 + k);
                short8 bv1 = *(const short8*)(pb1 + k);
                c00 = __builtin_amdgcn_mfma_f32_16x16x32_bf16(av0, bv0, c00, 0, 0, 0);
                c01 = __builtin_amdgcn_mfma_f32_16x16x32_bf16(av0, bv1, c01, 0, 0, 0);
                c10 = __builtin_amdgcn_mfma_f32_16x16x32_bf16(av1, bv0, c10, 0, 0, 0);
                c11 = __builtin_amdgcn_mfma_f32_16x16x32_bf16(av1, bv1, c11, 0, 0, 0);
            }
            float bb0 = cal_b3[n0 + lr], bb1 = cal_b3[n0 + 16 + lr];
            #pragma unroll
            for (int r = 0; r < 4; ++r) {
                int rl = quad * 4 + r, rh = rl + 16;
                delta[(size_t)(r0 + rl) * 256 + n0 + lr]      = c00[r] + bb0;
                delta[(size_t)(r0 + rl) * 256 + n0 + 16 + lr] = c01[r] + bb1;
                delta[(size_t)(r0 + rh) * 256 + n0 + lr]      = c10[r] + bb0;
                delta[(size_t)(r0 + rh) * 256 + n0 + 16 + lr] = c11[r] + bb1;
            }
        }
    }
}

// ================ K4: write calibrated [P,T,D] + out_is, NT stores ============
__global__ void finalize_k(const float* __restrict__ pc, const float* __restrict__ delta,
                           const float* __restrict__ strength, const float* __restrict__ colsum,
                           const float* __restrict__ proto, float* __restrict__ out,
                           float* __restrict__ out_is) {
    int p = blockIdx.x;
    int d4 = (threadIdx.x & 63) << 2;
    int t0 = threadIdx.x >> 6;
    bool dr = colsum[p] * (1.f / BB) > 0.3f;
    if (threadIdx.x == 0) out_is[p] = dr ? 1.f : 0.f;
    float* o = out + (size_t)p * TT * DD;
    if (dr) {
        float s = strength[p];
        float4 pcv = *(const float4*)(pc + (size_t)p * DD + d4);
        float4 dv  = *(const float4*)(delta + (size_t)p * DD + d4);
        float4 nc = make_float4(fmaf(s, dv.x, pcv.x), fmaf(s, dv.y, pcv.y),
                                fmaf(s, dv.z, pcv.z), fmaf(s, dv.w, pcv.w));
        #pragma unroll
        for (int t = t0; t < TT; t += 4)
            nt_store4(o + t * DD + d4, nc);
    } else {
        const float* pr = proto + (size_t)p * TT * DD;
        #pragma unroll
        for (int t = t0; t < TT; t += 4)
            nt_store4(o + t * DD + d4, nt_load4(pr + t * DD + d4));
    }
}

extern "C" void kernel_launch(void* const* d_in, const int* in_sizes, int n_in,
                              void* d_out, int out_size, void* d_ws, size_t ws_size,
                              hipStream_t stream) {
    const float* cf     = (const float*)d_in[0];
    const float* proto  = (const float*)d_in[1];
    const float* dd_w1  = (const float*)d_in[2];
    const float* dd_b1  = (const float*)d_in[3];
    const float* dd_g1  = (const float*)d_in[4];
    const float* dd_be1 = (const float*)d_in[5];
    const float* dd_w2  = (const float*)d_in[6];
    const float* dd_b2  = (const float*)d_in[7];
    const float* dd_w3  = (const float*)d_in[8];
    const float* dd_b3  = (const float*)d_in[9];
    const float* cal_w1 = (const float*)d_in[10];
    const float* cal_b1 = (const float*)d_in[11];
    const float* cal_g1 = (const float*)d_in[12];
    const float* cal_be1= (const float*)d_in[13];
    const float* cal_w2 = (const float*)d_in[14];
    const float* cal_b2 = (const float*)d_in[15];
    const float* cal_w3 = (const float*)d_in[16];
    const float* cal_b3 = (const float*)d_in[17];

    float* out_cal   = (float*)d_out;
    float* out_drift = out_cal + (size_t)PP * TT * DD;
    float* out_is    = out_drift + (size_t)BB * PP;

    float* w = (float*)d_ws;
    float* colsum   = w;               // 2048 (zeroed inside prep_k)
    float* addvec   = w + 4096;        // 512
    float* fn       = w + 4608;        // 1024
    float* pn       = w + 5632;        // 2048
    float* strength = w + 7680;        // 2048
    float* pc       = w + 9728;        // 2048*256
    float* ffm      = w + 534016;      // 1024*256 fp32 (gmean source)
    float* delta    = w + 2631168;     // 2048*256
    __hip_bfloat16* bb = (__hip_bfloat16*)(w + 3155456);
    __hip_bfloat16* ffb     = bb;                 // 1024*256
    __hip_bfloat16* pcb     = bb + 262144;        // 2048*256
    __hip_bfloat16* w1cat   = bb + 786432;        // 1024*256
    __hip_bfloat16* w2dd    = bb + 1048576;       // 256*512
    __hip_bfloat16* w2cal   = bb + 1179648;       // 512*512
    __hip_bfloat16* w3cal   = bb + 1441792;       // 256*512

    prep_k<<<1536, 256, 0, stream>>>(cf, proto, dd_w1, dd_w2, cal_w1, cal_w2, cal_w3,
                                     ffm, fn, pn, pc, colsum, ffb, pcb,
                                     w1cat, w2dd, w2cal, w3cal);
    sim_addvec_k<<<514, 256, 0, stream>>>(ffb, pcb, fn, pn, ffm, dd_w1, dd_b1,
                                          out_drift, colsum, addvec);
    mlp_k<<<128, 256, 0, stream>>>(pcb, w1cat, addvec, cal_b1,
                                   dd_g1, dd_be1, cal_g1, cal_be1,
                                   w2dd, w2cal, dd_b2, cal_b2,
                                   w3cal, cal_b3, dd_w3, dd_b3,
                                   delta, strength);
    finalize_k<<<PP, 256, 0, stream>>>(pc, delta, strength, colsum, proto, out_cal, out_is);
}

// Round 5
// 378.415 us; speedup vs baseline: 1.1165x; 1.0563x over previous
//
#include <hip/hip_runtime.h>
#include <hip/hip_bf16.h>
#include <math.h>

#define BB 1024
#define TT 64
#define DD 256
#define PP 2048
#define HH 512

typedef __attribute__((ext_vector_type(8))) short short8;
typedef __attribute__((ext_vector_type(4))) short short4v;
typedef __attribute__((ext_vector_type(4))) float f32x4;
typedef __attribute__((address_space(3))) void as3_void;
typedef const __attribute__((address_space(1))) void as1_cvoid;

__device__ __forceinline__ void nt_store4(float* p, float4 v) {
    f32x4 t = {v.x, v.y, v.z, v.w};
    __builtin_nontemporal_store(t, (f32x4*)p);
}

__device__ __forceinline__ void nt_store1(float* p, float v) {
    __builtin_nontemporal_store(v, p);
}

__device__ __forceinline__ float4 nt_load4(const float* p) {
    f32x4 t = __builtin_nontemporal_load((const f32x4*)p);
    return make_float4(t.x, t.y, t.z, t.w);
}

// ================ K1: prep — DMA-staged row reduce (global_load_lds) ==========
// blocks 0..3071:    one [64,256] row each; stage 64KB to LDS via DMA, reduce.
// blocks 3072..3839: weight convert+transpose + colsum zero
__global__ void __launch_bounds__(256)
prep_k(const float* __restrict__ cf, const float* __restrict__ proto,
       const float* __restrict__ dd_w1, const float* __restrict__ dd_w2,
       const float* __restrict__ cal_w1, const float* __restrict__ cal_w2,
       const float* __restrict__ cal_w3,
       float* __restrict__ ffm, float* __restrict__ fn,
       float* __restrict__ pn, float* __restrict__ pc,
       float* __restrict__ colsum,
       __hip_bfloat16* __restrict__ ffb, __hip_bfloat16* __restrict__ pcb,
       __hip_bfloat16* __restrict__ w1cat, __hip_bfloat16* __restrict__ w2dd,
       __hip_bfloat16* __restrict__ w2cal, __hip_bfloat16* __restrict__ w3cal) {
    __shared__ float tile[TT * DD];   // 64 KB
    __shared__ float smr[1024];       // 4 KB
    int b = blockIdx.x, tid = threadIdx.x;
    if (b < 3072) {
        int wv = tid >> 6, lane = tid & 63;
        const float* base = (b < 1024) ? cf + (size_t)b * TT * DD
                                       : proto + (size_t)(b - 1024) * TT * DD;
        // stage: wave wv stages t-rows [16wv .. 16wv+15]; each instr = 1KB row
        #pragma unroll
        for (int j = 0; j < 16; ++j) {
            int t = (wv << 4) + j;
            __builtin_amdgcn_global_load_lds(
                (as1_cvoid*)(base + (t << 8) + (lane << 2)),
                (as3_void*)&tile[t << 8], 16, 0, 0);
        }
        __syncthreads();               // compiler drains vmcnt(0) before s_barrier
        // reduce: thread owns 4 cols (c4), phase t0; per-wave rows are uniform
        int c4 = tid & 63, t0 = tid >> 6;
        float4 s = make_float4(0.f, 0.f, 0.f, 0.f);
        #pragma unroll
        for (int t = t0; t < TT; t += 4) {
            float4 v = *(const float4*)&tile[(t << 8) + (c4 << 2)];
            s.x += v.x; s.y += v.y; s.z += v.z; s.w += v.w;
        }
        *(float4*)&smr[(t0 << 8) + (c4 << 2)] = s;
        __syncthreads();
        float m = (smr[tid] + smr[256 + tid] + smr[512 + tid] + smr[768 + tid]) * (1.f / TT);
        if (b < 1024) {
            ffm[(size_t)b * DD + tid] = m;
            ffb[(size_t)b * DD + tid] = __float2bfloat16(m);
        } else {
            int r = b - 1024;
            pc[(size_t)r * DD + tid] = m;
            pcb[(size_t)r * DD + tid] = __float2bfloat16(m);
        }
        __syncthreads();               // smr reads done before reuse
        float q = m * m;
        #pragma unroll
        for (int o = 32; o > 0; o >>= 1) q += __shfl_xor(q, o, 64);
        if (lane == 0) smr[wv] = q;
        __syncthreads();
        if (tid == 0) {
            float nv = fmaxf(sqrtf(smr[0] + smr[1] + smr[2] + smr[3]), 1e-8f);
            if (b < 1024) fn[b] = nv; else pn[b - 1024] = nv;
        }
    } else {                           // weight convert+transpose, 4 elems/thread
        int bb = b - 3072;
        if (bb < 8) colsum[bb * 256 + tid] = 0.f;
        #pragma unroll
        for (int i2 = 0; i2 < 4; ++i2) {
            int idx = bb * 1024 + i2 * 256 + tid;
            if (idx < 262144) {               // w1cat: dd_w1 | cal_w1, K=256 N=512 each
                int half = idx >> 17;
                int i = idx & 131071;
                int n = i & 511, k = i >> 9;
                const float* src = half ? cal_w1 : dd_w1;
                float x = __builtin_nontemporal_load(src + (size_t)k * 512 + n);
                w1cat[(size_t)(half * 512 + n) * 256 + k] = __float2bfloat16(x);
            } else if (idx < 393216) {        // w2dd: K=512 N=256
                int i = idx - 262144;
                int n = i & 255, k = i >> 8;
                float x = __builtin_nontemporal_load(dd_w2 + (size_t)k * 256 + n);
                w2dd[(size_t)n * 512 + k] = __float2bfloat16(x);
            } else if (idx < 655360) {        // w2cal: K=512 N=512
                int i = idx - 393216;
                int n = i & 511, k = i >> 9;
                float x = __builtin_nontemporal_load(cal_w2 + (size_t)k * 512 + n);
                w2cal[(size_t)n * 512 + k] = __float2bfloat16(x);
            } else {                          // w3cal: K=512 N=256
                int i = idx - 655360;
                int n = i & 255, k = i >> 8;
                float x = __builtin_nontemporal_load(cal_w3 + (size_t)k * 256 + n);
                w3cal[(size_t)n * 512 + k] = __float2bfloat16(x);
            }
        }
    }
}

// ================ K2: sim MFMA ∥ fused MLP, role by blockIdx ==================
// blocks 0..127:   mlp role (h=bid&1; rows (bid>>1)*32). dd blocks compute their
//                  own addvec from ffm+dd_w1 (preamble), so no dependency on sim.
// blocks 128..639: sim role (drift + colsum), 4 wids/block.
#define LS 520   // LDS row stride in bf16 (1040 B)
__global__ void __launch_bounds__(256)
simmlp_k(const __hip_bfloat16* __restrict__ A,   // ffb
         const __hip_bfloat16* __restrict__ Bt,  // pcb
         const float* __restrict__ fn, const float* __restrict__ pn,
         const float* __restrict__ ffm,
         const float* __restrict__ dd_w1, const float* __restrict__ dd_b1,
         const __hip_bfloat16* __restrict__ w1cat, const float* __restrict__ cal_b1,
         const float* __restrict__ gdd, const float* __restrict__ bedd,
         const float* __restrict__ gcal, const float* __restrict__ becal,
         const __hip_bfloat16* __restrict__ w2dd, const __hip_bfloat16* __restrict__ w2cal,
         const float* __restrict__ dd_b2, const float* __restrict__ cal_b2,
         const __hip_bfloat16* __restrict__ w3cal, const float* __restrict__ cal_b3,
         const float* __restrict__ dd_w3, const float* __restrict__ dd_b3,
         float* __restrict__ drift, float* __restrict__ colsum,
         float* __restrict__ delta, float* __restrict__ strength) {
    __shared__ __hip_bfloat16 act1[32 * LS];
    __shared__ __hip_bfloat16 act2[32 * LS];
    __shared__ float scratch[1024];     // gmean partials, then free
    __shared__ float gmk[256];
    __shared__ float addv[512];
    __shared__ float lds_s[4][32];
    __shared__ float lds_q[4][32];

    int tid = threadIdx.x;
    int wv = tid >> 6;
    int lane = tid & 63;
    int lr = lane & 15, quad = lane >> 4;

    if (blockIdx.x >= 128) {
        // ------------------------------ sim role ------------------------------
        int wid = ((blockIdx.x - 128) << 2) + wv;      // 0..2047
        int mw = wid >> 6, nw = wid & 63;
        int m0 = mw << 5, n0 = nw << 5;
        const __hip_bfloat16* pa0 = A + (size_t)(m0 + lr) * DD + quad * 8;
        const __hip_bfloat16* pa1 = pa0 + 16 * DD;
        const __hip_bfloat16* pb0 = Bt + (size_t)(n0 + lr) * DD + quad * 8;
        const __hip_bfloat16* pb1 = pb0 + 16 * DD;
        f32x4 acc00 = {0,0,0,0}, acc01 = {0,0,0,0}, acc10 = {0,0,0,0}, acc11 = {0,0,0,0};
        #pragma unroll
        for (int k = 0; k < DD; k += 32) {
            short8 a0 = *(const short8*)(pa0 + k);
            short8 a1 = *(const short8*)(pa1 + k);
            short8 b0 = *(const short8*)(pb0 + k);
            short8 b1 = *(const short8*)(pb1 + k);
            acc00 = __builtin_amdgcn_mfma_f32_16x16x32_bf16(a0, b0, acc00, 0, 0, 0);
            acc01 = __builtin_amdgcn_mfma_f32_16x16x32_bf16(a0, b1, acc01, 0, 0, 0);
            acc10 = __builtin_amdgcn_mfma_f32_16x16x32_bf16(a1, b0, acc10, 0, 0, 0);
            acc11 = __builtin_amdgcn_mfma_f32_16x16x32_bf16(a1, b1, acc11, 0, 0, 0);
        }
        int col0 = n0 + lr, col1 = col0 + 16;
        float ip0 = 1.f / pn[col0], ip1 = 1.f / pn[col1];
        float cs0 = 0.f, cs1 = 0.f;
        #pragma unroll
        for (int r = 0; r < 4; ++r) {
            int row0 = m0 + quad * 4 + r;
            int row1 = row0 + 16;
            float if0 = 1.f / fn[row0];
            float if1 = 1.f / fn[row1];
            float d00 = 1.f - acc00[r] * if0 * ip0;
            float d01 = 1.f - acc01[r] * if0 * ip1;
            float d10 = 1.f - acc10[r] * if1 * ip0;
            float d11 = 1.f - acc11[r] * if1 * ip1;
            nt_store1(&drift[(size_t)row0 * PP + col0], d00);
            nt_store1(&drift[(size_t)row0 * PP + col1], d01);
            nt_store1(&drift[(size_t)row1 * PP + col0], d10);
            nt_store1(&drift[(size_t)row1 * PP + col1], d11);
            cs0 += d00 + d10;
            cs1 += d01 + d11;
        }
        cs0 += __shfl_xor(cs0, 16, 64); cs0 += __shfl_xor(cs0, 32, 64);
        cs1 += __shfl_xor(cs1, 16, 64); cs1 += __shfl_xor(cs1, 32, 64);
        if (quad == 0) {
            atomicAdd(&colsum[col0], cs0);
            atomicAdd(&colsum[col1], cs1);
        }
        return;
    }

    // ------------------------------ mlp role --------------------------------
    int h  = blockIdx.x & 1;
    int r0 = (blockIdx.x >> 1) << 5;
    const float* g  = h ? gcal : gdd;
    const float* be = h ? becal : bedd;

    if (h == 0) {
        // preamble: gmean over ffm, then addvec = dd_b1 + gmean @ dd_w1[256:]
        int c4 = tid & 63, rg = tid >> 6;
        float4 a = make_float4(0.f, 0.f, 0.f, 0.f);
        const float* f = ffm + (size_t)(rg << 8) * DD + (c4 << 2);
        #pragma unroll 8
        for (int i = 0; i < 256; ++i) {
            float4 v = *(const float4*)(f + (size_t)i * DD);
            a.x += v.x; a.y += v.y; a.z += v.z; a.w += v.w;
        }
        *(float4*)&scratch[(rg << 8) + (c4 << 2)] = a;
        __syncthreads();
        gmk[tid] = (scratch[tid] + scratch[256 + tid] + scratch[512 + tid] + scratch[768 + tid])
                   * (1.f / BB);
        __syncthreads();
        float s0 = dd_b1[tid], s1 = dd_b1[tid + 256];
        #pragma unroll 8
        for (int k = 0; k < 256; ++k) {
            float gm = gmk[k];
            s0 = fmaf(gm, dd_w1[(size_t)(256 + k) * 512 + tid], s0);
            s1 = fmaf(gm, dd_w1[(size_t)(256 + k) * 512 + tid + 256], s1);
        }
        addv[tid] = s0;
        addv[tid + 256] = s1;
        __syncthreads();
    }

    // ---------------- phase 1: layer1 GEMM ----------------
    const __hip_bfloat16* pa0 = Bt + (size_t)(r0 + lr) * DD + quad * 8;  // pcb
    const __hip_bfloat16* pa1 = pa0 + 16 * DD;
    f32x4 a00[4], a01[4], a10[4], a11[4];
    float bi0[4], bi1[4];
    #pragma unroll
    for (int t = 0; t < 4; ++t) {
        int n0g = h * 512 + wv * 128 + t * 32;
        const __hip_bfloat16* pb0 = w1cat + (size_t)(n0g + lr) * DD + quad * 8;
        const __hip_bfloat16* pb1 = pb0 + 16 * DD;
        f32x4 c00 = {0,0,0,0}, c01 = {0,0,0,0}, c10 = {0,0,0,0}, c11 = {0,0,0,0};
        #pragma unroll
        for (int k = 0; k < DD; k += 32) {
            short8 av0 = *(const short8*)(pa0 + k);
            short8 av1 = *(const short8*)(pa1 + k);
            short8 bv0 = *(const short8*)(pb0 + k);
            short8 bv1 = *(const short8*)(pb1 + k);
            c00 = __builtin_amdgcn_mfma_f32_16x16x32_bf16(av0, bv0, c00, 0, 0, 0);
            c01 = __builtin_amdgcn_mfma_f32_16x16x32_bf16(av0, bv1, c01, 0, 0, 0);
            c10 = __builtin_amdgcn_mfma_f32_16x16x32_bf16(av1, bv0, c10, 0, 0, 0);
            c11 = __builtin_amdgcn_mfma_f32_16x16x32_bf16(av1, bv1, c11, 0, 0, 0);
        }
        a00[t] = c00; a01[t] = c01; a10[t] = c10; a11[t] = c11;
        int cl0 = wv * 128 + t * 32 + lr;
        bi0[t] = h ? cal_b1[cl0] : addv[cl0];
        bi1[t] = h ? cal_b1[cl0 + 16] : addv[cl0 + 16];
    }
    float ps_lo[4] = {0,0,0,0}, pq_lo[4] = {0,0,0,0};
    float ps_hi[4] = {0,0,0,0}, pq_hi[4] = {0,0,0,0};
    #pragma unroll
    for (int t = 0; t < 4; ++t) {
        #pragma unroll
        for (int r = 0; r < 4; ++r) {
            float v00 = a00[t][r] + bi0[t];
            float v01 = a01[t][r] + bi1[t];
            float v10 = a10[t][r] + bi0[t];
            float v11 = a11[t][r] + bi1[t];
            a00[t][r] = v00; a01[t][r] = v01; a10[t][r] = v10; a11[t][r] = v11;
            ps_lo[r] += v00 + v01;  pq_lo[r] += v00 * v00 + v01 * v01;
            ps_hi[r] += v10 + v11;  pq_hi[r] += v10 * v10 + v11 * v11;
        }
    }
    #pragma unroll
    for (int mset = 1; mset < 16; mset <<= 1) {
        #pragma unroll
        for (int r = 0; r < 4; ++r) {
            ps_lo[r] += __shfl_xor(ps_lo[r], mset, 64);
            pq_lo[r] += __shfl_xor(pq_lo[r], mset, 64);
            ps_hi[r] += __shfl_xor(ps_hi[r], mset, 64);
            pq_hi[r] += __shfl_xor(pq_hi[r], mset, 64);
        }
    }
    if (lr < 8) {
        int rr = quad * 4 + (lr & 3) + ((lr >> 2) << 4);
        lds_s[wv][rr] = (lr >= 4) ? ps_hi[lr & 3] : ps_lo[lr & 3];
        lds_q[wv][rr] = (lr >= 4) ? pq_hi[lr & 3] : pq_lo[lr & 3];
    }
    __syncthreads();

    float mu_lo[4], rs_lo[4], mu_hi[4], rs_hi[4];
    #pragma unroll
    for (int r = 0; r < 4; ++r) {
        int rl = quad * 4 + r;
        float s = lds_s[0][rl] + lds_s[1][rl] + lds_s[2][rl] + lds_s[3][rl];
        float q = lds_q[0][rl] + lds_q[1][rl] + lds_q[2][rl] + lds_q[3][rl];
        float mu = s * (1.f / HH);
        float var = fmaxf(q * (1.f / HH) - mu * mu, 0.f);
        mu_lo[r] = mu; rs_lo[r] = rsqrtf(var + 1e-5f);
        int rh = rl + 16;
        s = lds_s[0][rh] + lds_s[1][rh] + lds_s[2][rh] + lds_s[3][rh];
        q = lds_q[0][rh] + lds_q[1][rh] + lds_q[2][rh] + lds_q[3][rh];
        mu = s * (1.f / HH);
        var = fmaxf(q * (1.f / HH) - mu * mu, 0.f);
        mu_hi[r] = mu; rs_hi[r] = rsqrtf(var + 1e-5f);
    }
    #pragma unroll
    for (int t = 0; t < 4; ++t) {
        int c0 = wv * 128 + t * 32 + lr, c1 = c0 + 16;
        float g0 = g[c0], g1 = g[c1], b0 = be[c0], b1 = be[c1];
        #pragma unroll
        for (int r = 0; r < 4; ++r) {
            int rl = quad * 4 + r, rh = rl + 16;
            act1[rl * LS + c0] = __float2bfloat16(fmaxf((a00[t][r] - mu_lo[r]) * rs_lo[r] * g0 + b0, 0.f));
            act1[rl * LS + c1] = __float2bfloat16(fmaxf((a01[t][r] - mu_lo[r]) * rs_lo[r] * g1 + b1, 0.f));
            act1[rh * LS + c0] = __float2bfloat16(fmaxf((a10[t][r] - mu_hi[r]) * rs_hi[r] * g0 + b0, 0.f));
            act1[rh * LS + c1] = __float2bfloat16(fmaxf((a11[t][r] - mu_hi[r]) * rs_hi[r] * g1 + b1, 0.f));
        }
    }
    __syncthreads();

    // ---------------- phase 2: layer2 GEMM (K=512) + ReLU -> act2 -------------
    {
        const __hip_bfloat16* w2 = h ? w2cal : w2dd;
        const float* b2 = h ? cal_b2 : dd_b2;
        int nt2 = h ? 4 : 2;
        #pragma unroll
        for (int tt = 0; tt < 4; ++tt) {
            if (tt < nt2) {
                int n0 = wv * (nt2 << 5) + (tt << 5);
                const __hip_bfloat16* pb0 = w2 + (size_t)(n0 + lr) * 512 + quad * 8;
                const __hip_bfloat16* pb1 = pb0 + 16 * 512;
                f32x4 c00 = {0,0,0,0}, c01 = {0,0,0,0}, c10 = {0,0,0,0}, c11 = {0,0,0,0};
                #pragma unroll
                for (int k = 0; k < 512; k += 32) {
                    short8 av0 = *(const short8*)&act1[lr * LS + quad * 8 + k];
                    short8 av1 = *(const short8*)&act1[(lr + 16) * LS + quad * 8 + k];
                    short8 bv0 = *(const short8*)(pb0 + k);
                    short8 bv1 = *(const short8*)(pb1 + k);
                    c00 = __builtin_amdgcn_mfma_f32_16x16x32_bf16(av0, bv0, c00, 0, 0, 0);
                    c01 = __builtin_amdgcn_mfma_f32_16x16x32_bf16(av0, bv1, c01, 0, 0, 0);
                    c10 = __builtin_amdgcn_mfma_f32_16x16x32_bf16(av1, bv0, c10, 0, 0, 0);
                    c11 = __builtin_amdgcn_mfma_f32_16x16x32_bf16(av1, bv1, c11, 0, 0, 0);
                }
                float bb0 = b2[n0 + lr], bb1 = b2[n0 + 16 + lr];
                #pragma unroll
                for (int r = 0; r < 4; ++r) {
                    int rl = quad * 4 + r, rh = rl + 16;
                    act2[rl * LS + n0 + lr]      = __float2bfloat16(fmaxf(c00[r] + bb0, 0.f));
                    act2[rl * LS + n0 + 16 + lr] = __float2bfloat16(fmaxf(c01[r] + bb1, 0.f));
                    act2[rh * LS + n0 + lr]      = __float2bfloat16(fmaxf(c10[r] + bb0, 0.f));
                    act2[rh * LS + n0 + 16 + lr] = __float2bfloat16(fmaxf(c11[r] + bb1, 0.f));
                }
            }
        }
    }
    __syncthreads();

    // ---------------- phase 3 ----------------
    if (h == 0) {
        int r = tid >> 3, e = tid & 7;
        float s = 0.f;
        #pragma unroll 8
        for (int c = 0; c < 32; ++c) {
            int cc = e * 32 + c;
            s += __bfloat162float(act2[r * LS + cc]) * dd_w3[cc];
        }
        s += __shfl_down(s, 4, 8);
        s += __shfl_down(s, 2, 8);
        s += __shfl_down(s, 1, 8);
        if (e == 0) {
            float conf = 1.f / (1.f + expf(-(s + dd_b3[0])));
            strength[r0 + r] = fminf(fmaxf(0.1f * conf, 0.f), 0.5f);
        }
    } else {
        #pragma unroll
        for (int tt = 0; tt < 2; ++tt) {
            int n0 = (wv << 6) + (tt << 5);
            const __hip_bfloat16* pb0 = w3cal + (size_t)(n0 + lr) * 512 + quad * 8;
            const __hip_bfloat16* pb1 = pb0 + 16 * 512;
            f32x4 c00 = {0,0,0,0}, c01 = {0,0,0,0}, c10 = {0,0,0,0}, c11 = {0,0,0,0};
            #pragma unroll
            for (int k = 0; k < 512; k += 32) {
                short8 av0 = *(const short8*)&act2[lr * LS + quad * 8 + k];
                short8 av1 = *(const short8*)&act2[(lr + 16) * LS + quad * 8 + k];
                short8 bv0 = *(const short8*)(pb0 + k);
                short8 bv1 = *(const short8*)(pb1 + k);
                c00 = __builtin_amdgcn_mfma_f32_16x16x32_bf16(av0, bv0, c00, 0, 0, 0);
                c01 = __builtin_amdgcn_mfma_f32_16x16x32_bf16(av0, bv1, c01, 0, 0, 0);
                c10 = __builtin_amdgcn_mfma_f32_16x16x32_bf16(av1, bv0, c10, 0, 0, 0);
                c11 = __builtin_amdgcn_mfma_f32_16x16x32_bf16(av1, bv1, c11, 0, 0, 0);
            }
            float bb0 = cal_b3[n0 + lr], bb1 = cal_b3[n0 + 16 + lr];
            #pragma unroll
            for (int r = 0; r < 4; ++r) {
                int rl = quad * 4 + r, rh = rl + 16;
                delta[(size_t)(r0 + rl) * 256 + n0 + lr]      = c00[r] + bb0;
                delta[(size_t)(r0 + rl) * 256 + n0 + 16 + lr] = c01[r] + bb1;
                delta[(size_t)(r0 + rh) * 256 + n0 + lr]      = c10[r] + bb0;
                delta[(size_t)(r0 + rh) * 256 + n0 + 16 + lr] = c11[r] + bb1;
            }
        }
    }
}

// ================ K3: write calibrated [P,T,D] + out_is, NT stores ============
__global__ void finalize_k(const float* __restrict__ pc, const float* __restrict__ delta,
                           const float* __restrict__ strength, const float* __restrict__ colsum,
                           const float* __restrict__ proto, float* __restrict__ out,
                           float* __restrict__ out_is) {
    int p = blockIdx.x;
    int d4 = (threadIdx.x & 63) << 2;
    int t0 = threadIdx.x >> 6;
    bool dr = colsum[p] * (1.f / BB) > 0.3f;
    if (threadIdx.x == 0) out_is[p] = dr ? 1.f : 0.f;
    float* o = out + (size_t)p * TT * DD;
    if (dr) {
        float s = strength[p];
        float4 pcv = *(const float4*)(pc + (size_t)p * DD + d4);
        float4 dv  = *(const float4*)(delta + (size_t)p * DD + d4);
        float4 nc = make_float4(fmaf(s, dv.x, pcv.x), fmaf(s, dv.y, pcv.y),
                                fmaf(s, dv.z, pcv.z), fmaf(s, dv.w, pcv.w));
        #pragma unroll
        for (int t = t0; t < TT; t += 4)
            nt_store4(o + t * DD + d4, nc);
    } else {
        const float* pr = proto + (size_t)p * TT * DD;
        #pragma unroll
        for (int t = t0; t < TT; t += 4)
            nt_store4(o + t * DD + d4, nt_load4(pr + t * DD + d4));
    }
}

extern "C" void kernel_launch(void* const* d_in, const int* in_sizes, int n_in,
                              void* d_out, int out_size, void* d_ws, size_t ws_size,
                              hipStream_t stream) {
    const float* cf     = (const float*)d_in[0];
    const float* proto  = (const float*)d_in[1];
    const float* dd_w1  = (const float*)d_in[2];
    const float* dd_b1  = (const float*)d_in[3];
    const float* dd_g1  = (const float*)d_in[4];
    const float* dd_be1 = (const float*)d_in[5];
    const float* dd_w2  = (const float*)d_in[6];
    const float* dd_b2  = (const float*)d_in[7];
    const float* dd_w3  = (const float*)d_in[8];
    const float* dd_b3  = (const float*)d_in[9];
    const float* cal_w1 = (const float*)d_in[10];
    const float* cal_b1 = (const float*)d_in[11];
    const float* cal_g1 = (const float*)d_in[12];
    const float* cal_be1= (const float*)d_in[13];
    const float* cal_w2 = (const float*)d_in[14];
    const float* cal_b2 = (const float*)d_in[15];
    const float* cal_w3 = (const float*)d_in[16];
    const float* cal_b3 = (const float*)d_in[17];

    float* out_cal   = (float*)d_out;
    float* out_drift = out_cal + (size_t)PP * TT * DD;
    float* out_is    = out_drift + (size_t)BB * PP;

    float* w = (float*)d_ws;
    float* colsum   = w;               // 2048 (zeroed inside prep_k)
    float* fn       = w + 4608;        // 1024
    float* pn       = w + 5632;        // 2048
    float* strength = w + 7680;        // 2048
    float* pc       = w + 9728;        // 2048*256
    float* ffm      = w + 534016;      // 1024*256 fp32 (gmean source)
    float* delta    = w + 2631168;     // 2048*256
    __hip_bfloat16* bb = (__hip_bfloat16*)(w + 3155456);
    __hip_bfloat16* ffb     = bb;                 // 1024*256
    __hip_bfloat16* pcb     = bb + 262144;        // 2048*256
    __hip_bfloat16* w1cat   = bb + 786432;        // 1024*256
    __hip_bfloat16* w2dd    = bb + 1048576;       // 256*512
    __hip_bfloat16* w2cal   = bb + 1179648;       // 512*512
    __hip_bfloat16* w3cal   = bb + 1441792;       // 256*512

    prep_k<<<3840, 256, 0, stream>>>(cf, proto, dd_w1, dd_w2, cal_w1, cal_w2, cal_w3,
                                     ffm, fn, pn, pc, colsum, ffb, pcb,
                                     w1cat, w2dd, w2cal, w3cal);
    simmlp_k<<<640, 256, 0, stream>>>(ffb, pcb, fn, pn, ffm, dd_w1, dd_b1,
                                      w1cat, cal_b1,
                                      dd_g1, dd_be1, cal_g1, cal_be1,
                                      w2dd, w2cal, dd_b2, cal_b2,
                                      w3cal, cal_b3, dd_w3, dd_b3,
                                      out_drift, colsum, delta, strength);
    finalize_k<<<PP, 256, 0, stream>>>(pc, delta, strength, colsum, proto, out_cal, out_is);
}

// Round 6
// 376.415 us; speedup vs baseline: 1.1225x; 1.0053x over previous
//
#include <hip/hip_runtime.h>
#include <hip/hip_bf16.h>
#include <math.h>

#define BB 1024
#define TT 64
#define DD 256
#define PP 2048
#define HH 512

typedef __attribute__((ext_vector_type(8))) short short8;
typedef __attribute__((ext_vector_type(4))) short short4v;
typedef __attribute__((ext_vector_type(4))) float f32x4;
typedef __attribute__((address_space(3))) void as3_void;
typedef const __attribute__((address_space(1))) void as1_cvoid;

__device__ __forceinline__ void nt_store4(float* p, float4 v) {
    f32x4 t = {v.x, v.y, v.z, v.w};
    __builtin_nontemporal_store(t, (f32x4*)p);
}

__device__ __forceinline__ void nt_store1(float* p, float v) {
    __builtin_nontemporal_store(v, p);
}

__device__ __forceinline__ float4 nt_load4(const float* p) {
    f32x4 t = __builtin_nontemporal_load((const f32x4*)p);
    return make_float4(t.x, t.y, t.z, t.w);
}

// ================ K1: prep — wave-local DMA pipeline (no stage barrier) =======
// blocks 0..3071:    one [64,256] row each. Wave wv owns t-rows [16wv,16wv+16):
//                    stages them via global_load_lds, reduces them itself with
//                    counted wave-local vmcnt (8-deep pipeline). One barrier for
//                    the 4-way cross-wave combine.
// blocks 3072..3839: weight convert+transpose + colsum zero
__global__ void __launch_bounds__(256)
prep_k(const float* __restrict__ cf, const float* __restrict__ proto,
       const float* __restrict__ dd_w1, const float* __restrict__ dd_w2,
       const float* __restrict__ cal_w1, const float* __restrict__ cal_w2,
       const float* __restrict__ cal_w3,
       float* __restrict__ ffm, float* __restrict__ fn,
       float* __restrict__ pn, float* __restrict__ pc,
       float* __restrict__ colsum,
       __hip_bfloat16* __restrict__ ffb, __hip_bfloat16* __restrict__ pcb,
       __hip_bfloat16* __restrict__ w1cat, __hip_bfloat16* __restrict__ w2dd,
       __hip_bfloat16* __restrict__ w2cal, __hip_bfloat16* __restrict__ w3cal) {
    __shared__ float tile[TT * DD];   // 64 KB
    __shared__ float smr[1024];       // 4 KB partials
    int b = blockIdx.x, tid = threadIdx.x;
    if (b < 3072) {
        int wv = tid >> 6, lane = tid & 63;
        const float* base = (b < 1024) ? cf + (size_t)b * TT * DD
                                       : proto + (size_t)(b - 1024) * TT * DD;
        // wave wv stages + reduces t-rows [16wv .. 16wv+15]
        const float* src = base + ((wv << 4) << 8) + (lane << 2);
        float* wtile = &tile[(wv << 4) << 8];
        #pragma unroll
        for (int j = 0; j < 16; ++j) {
            __builtin_amdgcn_global_load_lds(
                (as1_cvoid*)(src + (size_t)(j << 8)),
                (as3_void*)(wtile + (j << 8)), 16, 0, 0);
        }
        float4 s = make_float4(0.f, 0.f, 0.f, 0.f);
        // wave-local: first 8 rows landed once <=8 remain outstanding
        asm volatile("s_waitcnt vmcnt(8)" ::: "memory");
        __builtin_amdgcn_sched_barrier(0);
        #pragma unroll
        for (int j = 0; j < 8; ++j) {
            float4 v = *(const float4*)&wtile[(j << 8) + (lane << 2)];
            s.x += v.x; s.y += v.y; s.z += v.z; s.w += v.w;
        }
        asm volatile("s_waitcnt vmcnt(0)" ::: "memory");
        __builtin_amdgcn_sched_barrier(0);
        #pragma unroll
        for (int j = 8; j < 16; ++j) {
            float4 v = *(const float4*)&wtile[(j << 8) + (lane << 2)];
            s.x += v.x; s.y += v.y; s.z += v.z; s.w += v.w;
        }
        // publish this wave's 256-col partial
        *(float4*)&smr[(wv << 8) + (lane << 2)] = s;
        __syncthreads();
        // thread owns col = tid: combine 4 wave partials
        float m = (smr[tid] + smr[256 + tid] + smr[512 + tid] + smr[768 + tid]) * (1.f / TT);
        if (b < 1024) {
            ffm[(size_t)b * DD + tid] = m;
            ffb[(size_t)b * DD + tid] = __float2bfloat16(m);
        } else {
            int r = b - 1024;
            pc[(size_t)r * DD + tid] = m;
            pcb[(size_t)r * DD + tid] = __float2bfloat16(m);
        }
        __syncthreads();               // smr reads done before reuse
        float q = m * m;
        #pragma unroll
        for (int o = 32; o > 0; o >>= 1) q += __shfl_xor(q, o, 64);
        if (lane == 0) smr[wv] = q;
        __syncthreads();
        if (tid == 0) {
            float nv = fmaxf(sqrtf(smr[0] + smr[1] + smr[2] + smr[3]), 1e-8f);
            if (b < 1024) fn[b] = nv; else pn[b - 1024] = nv;
        }
    } else {                           // weight convert+transpose, 4 elems/thread
        int bb = b - 3072;
        if (bb < 8) colsum[bb * 256 + tid] = 0.f;
        #pragma unroll
        for (int i2 = 0; i2 < 4; ++i2) {
            int idx = bb * 1024 + i2 * 256 + tid;
            if (idx < 262144) {               // w1cat: dd_w1 | cal_w1, K=256 N=512 each
                int half = idx >> 17;
                int i = idx & 131071;
                int n = i & 511, k = i >> 9;
                const float* src = half ? cal_w1 : dd_w1;
                float x = __builtin_nontemporal_load(src + (size_t)k * 512 + n);
                w1cat[(size_t)(half * 512 + n) * 256 + k] = __float2bfloat16(x);
            } else if (idx < 393216) {        // w2dd: K=512 N=256
                int i = idx - 262144;
                int n = i & 255, k = i >> 8;
                float x = __builtin_nontemporal_load(dd_w2 + (size_t)k * 256 + n);
                w2dd[(size_t)n * 512 + k] = __float2bfloat16(x);
            } else if (idx < 655360) {        // w2cal: K=512 N=512
                int i = idx - 393216;
                int n = i & 511, k = i >> 9;
                float x = __builtin_nontemporal_load(cal_w2 + (size_t)k * 512 + n);
                w2cal[(size_t)n * 512 + k] = __float2bfloat16(x);
            } else {                          // w3cal: K=512 N=256
                int i = idx - 655360;
                int n = i & 255, k = i >> 8;
                float x = __builtin_nontemporal_load(cal_w3 + (size_t)k * 256 + n);
                w3cal[(size_t)n * 512 + k] = __float2bfloat16(x);
            }
        }
    }
}

// ================ K2: sim MFMA ∥ fused MLP, role by blockIdx ==================
#define LS 520   // LDS row stride in bf16 (1040 B)
__global__ void __launch_bounds__(256)
simmlp_k(const __hip_bfloat16* __restrict__ A,   // ffb
         const __hip_bfloat16* __restrict__ Bt,  // pcb
         const float* __restrict__ fn, const float* __restrict__ pn,
         const float* __restrict__ ffm,
         const float* __restrict__ dd_w1, const float* __restrict__ dd_b1,
         const __hip_bfloat16* __restrict__ w1cat, const float* __restrict__ cal_b1,
         const float* __restrict__ gdd, const float* __restrict__ bedd,
         const float* __restrict__ gcal, const float* __restrict__ becal,
         const __hip_bfloat16* __restrict__ w2dd, const __hip_bfloat16* __restrict__ w2cal,
         const float* __restrict__ dd_b2, const float* __restrict__ cal_b2,
         const __hip_bfloat16* __restrict__ w3cal, const float* __restrict__ cal_b3,
         const float* __restrict__ dd_w3, const float* __restrict__ dd_b3,
         float* __restrict__ drift, float* __restrict__ colsum,
         float* __restrict__ delta, float* __restrict__ strength) {
    __shared__ __hip_bfloat16 act1[32 * LS];
    __shared__ __hip_bfloat16 act2[32 * LS];
    __shared__ float scratch[1024];
    __shared__ float gmk[256];
    __shared__ float addv[512];
    __shared__ float lds_s[4][32];
    __shared__ float lds_q[4][32];

    int tid = threadIdx.x;
    int wv = tid >> 6;
    int lane = tid & 63;
    int lr = lane & 15, quad = lane >> 4;

    if (blockIdx.x >= 128) {
        // ------------------------------ sim role ------------------------------
        int wid = ((blockIdx.x - 128) << 2) + wv;      // 0..2047
        int mw = wid >> 6, nw = wid & 63;
        int m0 = mw << 5, n0 = nw << 5;
        const __hip_bfloat16* pa0 = A + (size_t)(m0 + lr) * DD + quad * 8;
        const __hip_bfloat16* pa1 = pa0 + 16 * DD;
        const __hip_bfloat16* pb0 = Bt + (size_t)(n0 + lr) * DD + quad * 8;
        const __hip_bfloat16* pb1 = pb0 + 16 * DD;
        f32x4 acc00 = {0,0,0,0}, acc01 = {0,0,0,0}, acc10 = {0,0,0,0}, acc11 = {0,0,0,0};
        #pragma unroll
        for (int k = 0; k < DD; k += 32) {
            short8 a0 = *(const short8*)(pa0 + k);
            short8 a1 = *(const short8*)(pa1 + k);
            short8 b0 = *(const short8*)(pb0 + k);
            short8 b1 = *(const short8*)(pb1 + k);
            acc00 = __builtin_amdgcn_mfma_f32_16x16x32_bf16(a0, b0, acc00, 0, 0, 0);
            acc01 = __builtin_amdgcn_mfma_f32_16x16x32_bf16(a0, b1, acc01, 0, 0, 0);
            acc10 = __builtin_amdgcn_mfma_f32_16x16x32_bf16(a1, b0, acc10, 0, 0, 0);
            acc11 = __builtin_amdgcn_mfma_f32_16x16x32_bf16(a1, b1, acc11, 0, 0, 0);
        }
        int col0 = n0 + lr, col1 = col0 + 16;
        float ip0 = 1.f / pn[col0], ip1 = 1.f / pn[col1];
        float cs0 = 0.f, cs1 = 0.f;
        #pragma unroll
        for (int r = 0; r < 4; ++r) {
            int row0 = m0 + quad * 4 + r;
            int row1 = row0 + 16;
            float if0 = 1.f / fn[row0];
            float if1 = 1.f / fn[row1];
            float d00 = 1.f - acc00[r] * if0 * ip0;
            float d01 = 1.f - acc01[r] * if0 * ip1;
            float d10 = 1.f - acc10[r] * if1 * ip0;
            float d11 = 1.f - acc11[r] * if1 * ip1;
            nt_store1(&drift[(size_t)row0 * PP + col0], d00);
            nt_store1(&drift[(size_t)row0 * PP + col1], d01);
            nt_store1(&drift[(size_t)row1 * PP + col0], d10);
            nt_store1(&drift[(size_t)row1 * PP + col1], d11);
            cs0 += d00 + d10;
            cs1 += d01 + d11;
        }
        cs0 += __shfl_xor(cs0, 16, 64); cs0 += __shfl_xor(cs0, 32, 64);
        cs1 += __shfl_xor(cs1, 16, 64); cs1 += __shfl_xor(cs1, 32, 64);
        if (quad == 0) {
            atomicAdd(&colsum[col0], cs0);
            atomicAdd(&colsum[col1], cs1);
        }
        return;
    }

    // ------------------------------ mlp role --------------------------------
    int h  = blockIdx.x & 1;
    int r0 = (blockIdx.x >> 1) << 5;
    const float* g  = h ? gcal : gdd;
    const float* be = h ? becal : bedd;

    if (h == 0) {
        int c4 = tid & 63, rg = tid >> 6;
        float4 a = make_float4(0.f, 0.f, 0.f, 0.f);
        const float* f = ffm + (size_t)(rg << 8) * DD + (c4 << 2);
        #pragma unroll 8
        for (int i = 0; i < 256; ++i) {
            float4 v = *(const float4*)(f + (size_t)i * DD);
            a.x += v.x; a.y += v.y; a.z += v.z; a.w += v.w;
        }
        *(float4*)&scratch[(rg << 8) + (c4 << 2)] = a;
        __syncthreads();
        gmk[tid] = (scratch[tid] + scratch[256 + tid] + scratch[512 + tid] + scratch[768 + tid])
                   * (1.f / BB);
        __syncthreads();
        float s0 = dd_b1[tid], s1 = dd_b1[tid + 256];
        #pragma unroll 8
        for (int k = 0; k < 256; ++k) {
            float gm = gmk[k];
            s0 = fmaf(gm, dd_w1[(size_t)(256 + k) * 512 + tid], s0);
            s1 = fmaf(gm, dd_w1[(size_t)(256 + k) * 512 + tid + 256], s1);
        }
        addv[tid] = s0;
        addv[tid + 256] = s1;
        __syncthreads();
    }

    // ---------------- phase 1: layer1 GEMM ----------------
    const __hip_bfloat16* pa0 = Bt + (size_t)(r0 + lr) * DD + quad * 8;  // pcb
    const __hip_bfloat16* pa1 = pa0 + 16 * DD;
    f32x4 a00[4], a01[4], a10[4], a11[4];
    float bi0[4], bi1[4];
    #pragma unroll
    for (int t = 0; t < 4; ++t) {
        int n0g = h * 512 + wv * 128 + t * 32;
        const __hip_bfloat16* pb0 = w1cat + (size_t)(n0g + lr) * DD + quad * 8;
        const __hip_bfloat16* pb1 = pb0 + 16 * DD;
        f32x4 c00 = {0,0,0,0}, c01 = {0,0,0,0}, c10 = {0,0,0,0}, c11 = {0,0,0,0};
        #pragma unroll
        for (int k = 0; k < DD; k += 32) {
            short8 av0 = *(const short8*)(pa0 + k);
            short8 av1 = *(const short8*)(pa1 + k);
            short8 bv0 = *(const short8*)(pb0 + k);
            short8 bv1 = *(const short8*)(pb1 + k);
            c00 = __builtin_amdgcn_mfma_f32_16x16x32_bf16(av0, bv0, c00, 0, 0, 0);
            c01 = __builtin_amdgcn_mfma_f32_16x16x32_bf16(av0, bv1, c01, 0, 0, 0);
            c10 = __builtin_amdgcn_mfma_f32_16x16x32_bf16(av1, bv0, c10, 0, 0, 0);
            c11 = __builtin_amdgcn_mfma_f32_16x16x32_bf16(av1, bv1, c11, 0, 0, 0);
        }
        a00[t] = c00; a01[t] = c01; a10[t] = c10; a11[t] = c11;
        int cl0 = wv * 128 + t * 32 + lr;
        bi0[t] = h ? cal_b1[cl0] : addv[cl0];
        bi1[t] = h ? cal_b1[cl0 + 16] : addv[cl0 + 16];
    }
    float ps_lo[4] = {0,0,0,0}, pq_lo[4] = {0,0,0,0};
    float ps_hi[4] = {0,0,0,0}, pq_hi[4] = {0,0,0,0};
    #pragma unroll
    for (int t = 0; t < 4; ++t) {
        #pragma unroll
        for (int r = 0; r < 4; ++r) {
            float v00 = a00[t][r] + bi0[t];
            float v01 = a01[t][r] + bi1[t];
            float v10 = a10[t][r] + bi0[t];
            float v11 = a11[t][r] + bi1[t];
            a00[t][r] = v00; a01[t][r] = v01; a10[t][r] = v10; a11[t][r] = v11;
            ps_lo[r] += v00 + v01;  pq_lo[r] += v00 * v00 + v01 * v01;
            ps_hi[r] += v10 + v11;  pq_hi[r] += v10 * v10 + v11 * v11;
        }
    }
    #pragma unroll
    for (int mset = 1; mset < 16; mset <<= 1) {
        #pragma unroll
        for (int r = 0; r < 4; ++r) {
            ps_lo[r] += __shfl_xor(ps_lo[r], mset, 64);
            pq_lo[r] += __shfl_xor(pq_lo[r], mset, 64);
            ps_hi[r] += __shfl_xor(ps_hi[r], mset, 64);
            pq_hi[r] += __shfl_xor(pq_hi[r], mset, 64);
        }
    }
    if (lr < 8) {
        int rr = quad * 4 + (lr & 3) + ((lr >> 2) << 4);
        lds_s[wv][rr] = (lr >= 4) ? ps_hi[lr & 3] : ps_lo[lr & 3];
        lds_q[wv][rr] = (lr >= 4) ? pq_hi[lr & 3] : pq_lo[lr & 3];
    }
    __syncthreads();

    float mu_lo[4], rs_lo[4], mu_hi[4], rs_hi[4];
    #pragma unroll
    for (int r = 0; r < 4; ++r) {
        int rl = quad * 4 + r;
        float s = lds_s[0][rl] + lds_s[1][rl] + lds_s[2][rl] + lds_s[3][rl];
        float q = lds_q[0][rl] + lds_q[1][rl] + lds_q[2][rl] + lds_q[3][rl];
        float mu = s * (1.f / HH);
        float var = fmaxf(q * (1.f / HH) - mu * mu, 0.f);
        mu_lo[r] = mu; rs_lo[r] = rsqrtf(var + 1e-5f);
        int rh = rl + 16;
        s = lds_s[0][rh] + lds_s[1][rh] + lds_s[2][rh] + lds_s[3][rh];
        q = lds_q[0][rh] + lds_q[1][rh] + lds_q[2][rh] + lds_q[3][rh];
        mu = s * (1.f / HH);
        var = fmaxf(q * (1.f / HH) - mu * mu, 0.f);
        mu_hi[r] = mu; rs_hi[r] = rsqrtf(var + 1e-5f);
    }
    #pragma unroll
    for (int t = 0; t < 4; ++t) {
        int c0 = wv * 128 + t * 32 + lr, c1 = c0 + 16;
        float g0 = g[c0], g1 = g[c1], b0 = be[c0], b1 = be[c1];
        #pragma unroll
        for (int r = 0; r < 4; ++r) {
            int rl = quad * 4 + r, rh = rl + 16;
            act1[rl * LS + c0] = __float2bfloat16(fmaxf((a00[t][r] - mu_lo[r]) * rs_lo[r] * g0 + b0, 0.f));
            act1[rl * LS + c1] = __float2bfloat16(fmaxf((a01[t][r] - mu_lo[r]) * rs_lo[r] * g1 + b1, 0.f));
            act1[rh * LS + c0] = __float2bfloat16(fmaxf((a10[t][r] - mu_hi[r]) * rs_hi[r] * g0 + b0, 0.f));
            act1[rh * LS + c1] = __float2bfloat16(fmaxf((a11[t][r] - mu_hi[r]) * rs_hi[r] * g1 + b1, 0.f));
        }
    }
    __syncthreads();

    // ---------------- phase 2: layer2 GEMM (K=512) + ReLU -> act2 -------------
    {
        const __hip_bfloat16* w2 = h ? w2cal : w2dd;
        const float* b2 = h ? cal_b2 : dd_b2;
        int nt2 = h ? 4 : 2;
        #pragma unroll
        for (int tt = 0; tt < 4; ++tt) {
            if (tt < nt2) {
                int n0 = wv * (nt2 << 5) + (tt << 5);
                const __hip_bfloat16* pb0 = w2 + (size_t)(n0 + lr) * 512 + quad * 8;
                const __hip_bfloat16* pb1 = pb0 + 16 * 512;
                f32x4 c00 = {0,0,0,0}, c01 = {0,0,0,0}, c10 = {0,0,0,0}, c11 = {0,0,0,0};
                #pragma unroll
                for (int k = 0; k < 512; k += 32) {
                    short8 av0 = *(const short8*)&act1[lr * LS + quad * 8 + k];
                    short8 av1 = *(const short8*)&act1[(lr + 16) * LS + quad * 8 + k];
                    short8 bv0 = *(const short8*)(pb0 + k);
                    short8 bv1 = *(const short8*)(pb1 + k);
                    c00 = __builtin_amdgcn_mfma_f32_16x16x32_bf16(av0, bv0, c00, 0, 0, 0);
                    c01 = __builtin_amdgcn_mfma_f32_16x16x32_bf16(av0, bv1, c01, 0, 0, 0);
                    c10 = __builtin_amdgcn_mfma_f32_16x16x32_bf16(av1, bv0, c10, 0, 0, 0);
                    c11 = __builtin_amdgcn_mfma_f32_16x16x32_bf16(av1, bv1, c11, 0, 0, 0);
                }
                float bb0 = b2[n0 + lr], bb1 = b2[n0 + 16 + lr];
                #pragma unroll
                for (int r = 0; r < 4; ++r) {
                    int rl = quad * 4 + r, rh = rl + 16;
                    act2[rl * LS + n0 + lr]      = __float2bfloat16(fmaxf(c00[r] + bb0, 0.f));
                    act2[rl * LS + n0 + 16 + lr] = __float2bfloat16(fmaxf(c01[r] + bb1, 0.f));
                    act2[rh * LS + n0 + lr]      = __float2bfloat16(fmaxf(c10[r] + bb0, 0.f));
                    act2[rh * LS + n0 + 16 + lr] = __float2bfloat16(fmaxf(c11[r] + bb1, 0.f));
                }
            }
        }
    }
    __syncthreads();

    // ---------------- phase 3 ----------------
    if (h == 0) {
        int r = tid >> 3, e = tid & 7;
        float s = 0.f;
        #pragma unroll 8
        for (int c = 0; c < 32; ++c) {
            int cc = e * 32 + c;
            s += __bfloat162float(act2[r * LS + cc]) * dd_w3[cc];
        }
        s += __shfl_down(s, 4, 8);
        s += __shfl_down(s, 2, 8);
        s += __shfl_down(s, 1, 8);
        if (e == 0) {
            float conf = 1.f / (1.f + expf(-(s + dd_b3[0])));
            strength[r0 + r] = fminf(fmaxf(0.1f * conf, 0.f), 0.5f);
        }
    } else {
        #pragma unroll
        for (int tt = 0; tt < 2; ++tt) {
            int n0 = (wv << 6) + (tt << 5);
            const __hip_bfloat16* pb0 = w3cal + (size_t)(n0 + lr) * 512 + quad * 8;
            const __hip_bfloat16* pb1 = pb0 + 16 * 512;
            f32x4 c00 = {0,0,0,0}, c01 = {0,0,0,0}, c10 = {0,0,0,0}, c11 = {0,0,0,0};
            #pragma unroll
            for (int k = 0; k < 512; k += 32) {
                short8 av0 = *(const short8*)&act2[lr * LS + quad * 8 + k];
                short8 av1 = *(const short8*)&act2[(lr + 16) * LS + quad * 8 + k];
                short8 bv0 = *(const short8*)(pb0 + k);
                short8 bv1 = *(const short8*)(pb1 + k);
                c00 = __builtin_amdgcn_mfma_f32_16x16x32_bf16(av0, bv0, c00, 0, 0, 0);
                c01 = __builtin_amdgcn_mfma_f32_16x16x32_bf16(av0, bv1, c01, 0, 0, 0);
                c10 = __builtin_amdgcn_mfma_f32_16x16x32_bf16(av1, bv0, c10, 0, 0, 0);
                c11 = __builtin_amdgcn_mfma_f32_16x16x32_bf16(av1, bv1, c11, 0, 0, 0);
            }
            float bb0 = cal_b3[n0 + lr], bb1 = cal_b3[n0 + 16 + lr];
            #pragma unroll
            for (int r = 0; r < 4; ++r) {
                int rl = quad * 4 + r, rh = rl + 16;
                delta[(size_t)(r0 + rl) * 256 + n0 + lr]      = c00[r] + bb0;
                delta[(size_t)(r0 + rl) * 256 + n0 + 16 + lr] = c01[r] + bb1;
                delta[(size_t)(r0 + rh) * 256 + n0 + lr]      = c10[r] + bb0;
                delta[(size_t)(r0 + rh) * 256 + n0 + 16 + lr] = c11[r] + bb1;
            }
        }
    }
}

// ================ K3: write calibrated [P,T,D] + out_is, NT stores ============
__global__ void finalize_k(const float* __restrict__ pc, const float* __restrict__ delta,
                           const float* __restrict__ strength, const float* __restrict__ colsum,
                           const float* __restrict__ proto, float* __restrict__ out,
                           float* __restrict__ out_is) {
    int p = blockIdx.x;
    int d4 = (threadIdx.x & 63) << 2;
    int t0 = threadIdx.x >> 6;
    bool dr = colsum[p] * (1.f / BB) > 0.3f;
    if (threadIdx.x == 0) out_is[p] = dr ? 1.f : 0.f;
    float* o = out + (size_t)p * TT * DD;
    if (dr) {
        float s = strength[p];
        float4 pcv = *(const float4*)(pc + (size_t)p * DD + d4);
        float4 dv  = *(const float4*)(delta + (size_t)p * DD + d4);
        float4 nc = make_float4(fmaf(s, dv.x, pcv.x), fmaf(s, dv.y, pcv.y),
                                fmaf(s, dv.z, pcv.z), fmaf(s, dv.w, pcv.w));
        #pragma unroll
        for (int t = t0; t < TT; t += 4)
            nt_store4(o + t * DD + d4, nc);
    } else {
        const float* pr = proto + (size_t)p * TT * DD;
        #pragma unroll
        for (int t = t0; t < TT; t += 4)
            nt_store4(o + t * DD + d4, nt_load4(pr + t * DD + d4));
    }
}

extern "C" void kernel_launch(void* const* d_in, const int* in_sizes, int n_in,
                              void* d_out, int out_size, void* d_ws, size_t ws_size,
                              hipStream_t stream) {
    const float* cf     = (const float*)d_in[0];
    const float* proto  = (const float*)d_in[1];
    const float* dd_w1  = (const float*)d_in[2];
    const float* dd_b1  = (const float*)d_in[3];
    const float* dd_g1  = (const float*)d_in[4];
    const float* dd_be1 = (const float*)d_in[5];
    const float* dd_w2  = (const float*)d_in[6];
    const float* dd_b2  = (const float*)d_in[7];
    const float* dd_w3  = (const float*)d_in[8];
    const float* dd_b3  = (const float*)d_in[9];
    const float* cal_w1 = (const float*)d_in[10];
    const float* cal_b1 = (const float*)d_in[11];
    const float* cal_g1 = (const float*)d_in[12];
    const float* cal_be1= (const float*)d_in[13];
    const float* cal_w2 = (const float*)d_in[14];
    const float* cal_b2 = (const float*)d_in[15];
    const float* cal_w3 = (const float*)d_in[16];
    const float* cal_b3 = (const float*)d_in[17];

    float* out_cal   = (float*)d_out;
    float* out_drift = out_cal + (size_t)PP * TT * DD;
    float* out_is    = out_drift + (size_t)BB * PP;

    float* w = (float*)d_ws;
    float* colsum   = w;               // 2048 (zeroed inside prep_k)
    float* fn       = w + 4608;        // 1024
    float* pn       = w + 5632;        // 2048
    float* strength = w + 7680;        // 2048
    float* pc       = w + 9728;        // 2048*256
    float* ffm      = w + 534016;      // 1024*256 fp32 (gmean source)
    float* delta    = w + 2631168;     // 2048*256
    __hip_bfloat16* bb = (__hip_bfloat16*)(w + 3155456);
    __hip_bfloat16* ffb     = bb;                 // 1024*256
    __hip_bfloat16* pcb     = bb + 262144;        // 2048*256
    __hip_bfloat16* w1cat   = bb + 786432;        // 1024*256
    __hip_bfloat16* w2dd    = bb + 1048576;       // 256*512
    __hip_bfloat16* w2cal   = bb + 1179648;       // 512*512
    __hip_bfloat16* w3cal   = bb + 1441792;       // 256*512

    prep_k<<<3840, 256, 0, stream>>>(cf, proto, dd_w1, dd_w2, cal_w1, cal_w2, cal_w3,
                                     ffm, fn, pn, pc, colsum, ffb, pcb,
                                     w1cat, w2dd, w2cal, w3cal);
    simmlp_k<<<640, 256, 0, stream>>>(ffb, pcb, fn, pn, ffm, dd_w1, dd_b1,
                                      w1cat, cal_b1,
                                      dd_g1, dd_be1, cal_g1, cal_be1,
                                      w2dd, w2cal, dd_b2, cal_b2,
                                      w3cal, cal_b3, dd_w3, dd_b3,
                                      out_drift, colsum, delta, strength);
    finalize_k<<<PP, 256, 0, stream>>>(pc, delta, strength, colsum, proto, out_cal, out_is);
}